// Round 7
// baseline (1233.387 us; speedup 1.0000x reference)
//
#include <hip/hip_runtime.h>
#include <math.h>

#define S_  5
#define B_  2
#define C_  128
#define N_  576
#define SB  10
#define NPAIR 40
#define C2  256

typedef short v8s __attribute__((ext_vector_type(8)));
typedef float v4f __attribute__((ext_vector_type(4)));

#define GLOBAL_AS __attribute__((address_space(1)))
#define LDS_AS    __attribute__((address_space(3)))

__device__ __forceinline__ unsigned short f2bf(float f) {
    union { float f; unsigned u; } v; v.f = f;
    unsigned r = (v.u + 0x7FFF + ((v.u >> 16) & 1)) >> 16;
    return (unsigned short)r;
}
__device__ __forceinline__ float bf2f(unsigned short h) {
    union { unsigned u; float f; } v; v.u = ((unsigned)h) << 16;
    return v.f;
}

// ------------------------------------------------------------------ weight packs
__global__ void pack3_kernel(const float* __restrict__ wf, const float* __restrict__ wh,
                             const float* __restrict__ wl, unsigned short* __restrict__ Wp3)
{
    int idx = blockIdx.x * 256 + threadIdx.x;
    if (idx >= 384 * 1152) return;
    int co = idx / 1152, k = idx % 1152;
    int tap = k >> 7, ci = k & 127;
    const float* w = (co < 128) ? wf : (co < 256) ? wh : wl;
    int c = co & 127;
    Wp3[idx] = f2bf(w[((size_t)c * 128 + ci) * 9 + tap]);
}
__global__ void pack5_kernel(const float* __restrict__ w, unsigned short* __restrict__ Wp, int M)
{
    int idx = blockIdx.x * 256 + threadIdx.x;
    if (idx >= M * 6400) return;
    int co = idx / 6400, k = idx % 6400;
    int tap = k >> 8, ci = k & 255;
    Wp[idx] = f2bf(w[((size_t)co * 256 + ci) * 25 + tap]);
}
__global__ void packWc_kernel(const float* __restrict__ w, unsigned short* __restrict__ o)
{
    int idx = blockIdx.x * 256 + threadIdx.x;
    if (idx < 128 * 128) o[idx] = f2bf(w[idx]);
}

// ---------------------------------------------- transpose-cast: [c][px] f32 -> [px][c] bf16
// zrp != null: multiply by r = sigmoid(sum_k zrp[k][128+c] + zrb[128+c])  (4 partial planes)
__global__ __launch_bounds__(256) void tc_kernel(
    const float* __restrict__ src, const float* __restrict__ zrp,
    const float* __restrict__ zrb,
    unsigned short* __restrict__ dst, unsigned short* __restrict__ dst2)
{
    const size_t PLANE = (size_t)SB * C2 * N_;
    __shared__ float tile[128][65];
    int img = blockIdx.y, px0 = blockIdx.x * 64, t = threadIdx.x;
    #pragma unroll
    for (int i = 0; i < 32; ++i) {
        int e = i * 256 + t; int ci = e >> 6; int px = e & 63;
        float v = src[((size_t)img * 128 + ci) * 576 + px0 + px];
        if (zrp) {
            size_t zi = ((size_t)img * C2 + 128 + ci) * 576 + px0 + px;
            float a = zrb[128 + ci];
            #pragma unroll
            for (int k = 0; k < 4; ++k) a += zrp[k * PLANE + zi];
            v *= 1.f / (1.f + __expf(-a));
        }
        tile[ci][px] = v;
        if (dst2) dst2[((size_t)img * 128 + ci) * 576 + px0 + px] = f2bf(v);
    }
    __syncthreads();
    #pragma unroll
    for (int i = 0; i < 32; ++i) {
        int e = i * 256 + t; int px = e >> 7; int ci = e & 127;
        dst[((size_t)img * 576 + px0 + px) * 128 + ci] = f2bf(tile[ci][px]);
    }
}

// ------------------------------------------------------ MFMA implicit-GEMM conv v4
// block tile: 128co x 64px, 4 waves (wave = 64co x 32px)
// B window: global_load_lds 16B, double-buffered LDS, swizzle via source permutation
// A weights: direct-global DEPTH-slot register ring; DEPTH MUST divide TAPS
//            (slot = tap % DEPTH must be consistent across the chunk boundary)
template<int TAPS, int R, int SPLITK, int MODE>
__global__ __launch_bounds__(256, 1) void conv_mfma(
    const unsigned short* __restrict__ srcA, const unsigned short* __restrict__ srcB,
    const unsigned short* __restrict__ Wp, int COUT,
    const float* __restrict__ b0, const float* __restrict__ b1, const float* __restrict__ b2,
    float* __restrict__ po,
    unsigned short* __restrict__ t0, unsigned short* __restrict__ t1,
    unsigned short* __restrict__ t2)
{
    constexpr int KD     = 2 * R + 1;
    constexpr int WR     = 4 + 2 * R;
    constexpr int WC     = 24 + 2 * R;
    constexpr int NPOS   = WR * WC;
    constexpr int NSLOT  = NPOS * 4;
    constexpr int CINT   = (SPLITK == 1) ? 128 : 256;   // total input channels
    constexpr int PART   = CINT / SPLITK;               // channels per K-part
    constexpr int NCH    = PART / 32;                   // 32-ci chunks per part
    constexpr int KTOT   = TAPS * CINT;
    constexpr int DEPTH  = (TAPS == 25) ? 5 : 3;        // divides TAPS
    constexpr int ROUNDS = (NSLOT + 255) / 256;
    __shared__ __align__(16) unsigned short Xs[2][NPOS * 32];

    int f   = blockIdx.x;
    int kk  = f % SPLITK;
    int cgb = f / SPLITK;
    int pxb = blockIdx.y;
    int img = blockIdx.z;
    int t = threadIdx.x;
    int wave = t >> 6, lane = t & 63;
    int quad = lane >> 4, l15 = lane & 15;
    int cgw = wave & 1, pgw = wave >> 1;
    int px0w = pxb * 64 + pgw * 32;
    int r0 = (pxb * 64) / 24;

    const int cibase = kk * PART;
    const unsigned short* src = (cibase >= 128) ? srcB : srcA;
    const int cioff = cibase & 127;
    const unsigned short* srcI = src + (size_t)img * 576 * 128;

    int posBase[2], pxs[2];
    #pragma unroll
    for (int s = 0; s < 2; ++s) {
        int px = px0w + s * 16 + l15;
        pxs[s] = px;
        int pr = px / 24, pc = px % 24;
        posBase[s] = (pr - r0 + R) * WC + pc + R;
    }

    const unsigned short* wRow = Wp + (size_t)(cgb * 128 + cgw * 64 + l15) * KTOT
                                 + cibase + quad * 8;

    // staging geometry precompute (per-lane global offset + validity per round)
    int goff[ROUNDS]; bool gok[ROUNDS];
    #pragma unroll
    for (int rr = 0; rr < ROUNDS; ++rr) {
        int idx = rr * 256 + wave * 64 + lane;
        int pos = idx >> 2, slot = idx & 3;
        int gr = slot ^ ((pos >> 1) & 3);
        int wr = pos / WC, wc = pos % WC;
        int grow = r0 - R + wr, gcol = wc - R;
        gok[rr] = (idx < NSLOT) && grow >= 0 && grow < 24 && gcol >= 0 && gcol < 24;
        goff[rr] = (grow * 24 + gcol) * 128 + gr * 8;
    }

    // zero both buffers (boundary slots stay zero forever)
    {
        v8s zv;
        #pragma unroll
        for (int j = 0; j < 8; ++j) zv[j] = 0;
        unsigned short* xsf = &Xs[0][0];
        for (int i = t; i < NPOS * 8; i += 256) *(v8s*)&xsf[(size_t)i * 8] = zv;
    }
    __syncthreads();

    auto stage = [&](int ch, int buf) {
        const unsigned short* sp = srcI + cioff + ch * 32;
        char* lbase = (char*)&Xs[buf][0];
        #pragma unroll
        for (int rr = 0; rr < ROUNDS; ++rr) {
            if (gok[rr]) {
                __builtin_amdgcn_global_load_lds(
                    (const GLOBAL_AS void*)(sp + goff[rr]),
                    (LDS_AS void*)(lbase + (size_t)(rr * 256 + wave * 64) * 16),
                    16, 0, 0);
            }
        }
    };

    v8s abuf[DEPTH][4];
    auto loadA = [&](int ch, int tap, int slot) {
        const unsigned short* p = wRow + ch * 32 + tap * CINT;
        #pragma unroll
        for (int c = 0; c < 4; ++c)
            abuf[slot][c] = *(const v8s*)(p + (size_t)c * 16 * KTOT);
    };

    v4f acc[4][2];
    #pragma unroll
    for (int c = 0; c < 4; ++c)
        #pragma unroll
        for (int s = 0; s < 2; ++s)
            #pragma unroll
            for (int r = 0; r < 4; ++r) acc[c][s][r] = 0.f;

    stage(0, 0);
    #pragma unroll
    for (int d = 0; d < DEPTH; ++d) loadA(0, d, d);
    __syncthreads();   // drains staging vmcnt before reads

    #pragma unroll 1
    for (int ch = 0; ch < NCH; ++ch) {
        if (ch + 1 < NCH) stage(ch + 1, (ch + 1) & 1);
        const unsigned short* XsBuf = &Xs[ch & 1][0];
        const int chn = (ch + 1 < NCH) ? ch + 1 : ch;   // clamped prefetch target

        #pragma unroll
        for (int tap = 0; tap < TAPS; ++tap) {
            const int slot = tap % DEPTH;               // consistent: DEPTH | TAPS
            const int dy = tap / KD - R, dx = tap % KD - R;
            const int doff = dy * WC + dx;
            v8s bfr[2];
            #pragma unroll
            for (int s = 0; s < 2; ++s) {
                int pos = posBase[s] + doff;
                bfr[s] = *(const v8s*)&XsBuf[pos * 32 + ((quad ^ ((pos >> 1) & 3)) << 3)];
            }
            #pragma unroll
            for (int c = 0; c < 4; ++c)
                #pragma unroll
                for (int s = 0; s < 2; ++s)
                    acc[c][s] = __builtin_amdgcn_mfma_f32_16x16x32_bf16(abuf[slot][c], bfr[s], acc[c][s], 0, 0, 0);
            // ring prefetch (slot just consumed); (tap+DEPTH)%DEPTH == slot
            if (tap + DEPTH < TAPS) loadA(ch, tap + DEPTH, slot);
            else                    loadA(chn, tap + DEPTH - TAPS, slot);
        }
        __syncthreads();   // staging of ch+1 drained; all reads of this buf done
    }

    if (MODE == 1) {
        float* out = po + (size_t)kk * ((size_t)SB * COUT * 576)
                   + ((size_t)img * COUT + cgb * 128) * 576;
        #pragma unroll
        for (int c = 0; c < 4; ++c)
            #pragma unroll
            for (int s = 0; s < 2; ++s)
                #pragma unroll
                for (int r = 0; r < 4; ++r) {
                    int col = cgw * 64 + c * 16 + quad * 4 + r;
                    out[(size_t)col * 576 + pxs[s]] = acc[c][s][r];
                }
    } else {
        const float* bp = (cgb == 0) ? b0 : (cgb == 1) ? b1 : b2;
        #pragma unroll
        for (int c = 0; c < 4; ++c)
            #pragma unroll
            for (int s = 0; s < 2; ++s)
                #pragma unroll
                for (int r = 0; r < 4; ++r) {
                    int col = cgw * 64 + c * 16 + quad * 4 + r;
                    float v = acc[c][s][r] + bp[col];
                    if (cgb == 0)      t0[((size_t)img * 576 + pxs[s]) * 128 + col] = f2bf(v);
                    else if (cgb == 1) t1[((size_t)img * 576 + pxs[s]) * 128 + col] = f2bf(v);
                    else               t2[((size_t)img * 128 + col) * 576 + pxs[s]] = f2bf(v);
                }
    }
}

// ---------------------------------------------------------------- yt (MFMA)
__global__ __launch_bounds__(256) void yt_mfma(
    const unsigned short* __restrict__ hT, const unsigned short* __restrict__ Wcb,
    unsigned short* __restrict__ ytT)
{
    int t = threadIdx.x, wave = t >> 6, lane = t & 63;
    int q = lane >> 4, l15 = lane & 15;
    int n0 = blockIdx.x * 16, img = blockIdx.y;
    v4f acc[2];
    #pragma unroll
    for (int ct = 0; ct < 2; ++ct)
        #pragma unroll
        for (int r = 0; r < 4; ++r) acc[ct][r] = 0.f;
    #pragma unroll
    for (int kk = 0; kk < 4; ++kk) {
        v8s b = *(const v8s*)(hT + ((size_t)img * 576 + n0 + l15) * 128 + kk * 32 + q * 8);
        #pragma unroll
        for (int ct = 0; ct < 2; ++ct) {
            v8s a = *(const v8s*)(Wcb + (size_t)((wave * 2 + ct) * 16 + l15) * 128 + kk * 32 + q * 8);
            acc[ct] = __builtin_amdgcn_mfma_f32_16x16x32_bf16(a, b, acc[ct], 0, 0, 0);
        }
    }
    #pragma unroll
    for (int ct = 0; ct < 2; ++ct) {
        unsigned short* op = ytT + ((size_t)img * 576 + n0 + l15) * 128 + (wave * 2 + ct) * 16 + q * 4;
        #pragma unroll
        for (int r = 0; r < 4; ++r) op[r] = f2bf(acc[ct][r]);
    }
}

// ---------------------------------------------------- MFMA flash attention
template<int MODE>
__global__ __launch_bounds__(256) void attn_mfma(
    const unsigned short* __restrict__ QT, const unsigned short* __restrict__ KT,
    const unsigned short* __restrict__ Vc, float* __restrict__ Of,
    unsigned short* __restrict__ Oh, const float* __restrict__ addsrc,
    const float* __restrict__ alpha)
{
    __shared__ __align__(16) unsigned short P[16 * 576];
    __shared__ float redmx[4][16];
    __shared__ float redsm[4][16];
    int t = threadIdx.x;
    int wave = t >> 6, lane = t & 63;
    int q = lane >> 4, l15 = lane & 15;
    int n0 = blockIdx.x * 16;
    int p = blockIdx.y;
    int qimg, kimg;
    if (MODE == 0) { qimg = p; kimg = p; }
    else {
        int b = p & 1; int ij = p >> 1; int i = ij >> 2; int jj = ij & 3;
        int j = jj + (jj >= i ? 1 : 0);
        qimg = i * 2 + b; kimg = j * 2 + b;
    }
    const unsigned short* Qp = QT + ((size_t)qimg * 576 + n0) * 128;
    const unsigned short* Kp = KT + (size_t)kimg * 576 * 128;
    const unsigned short* Vp = Vc + (size_t)kimg * 128 * 576;

    v8s aq[4];
    #pragma unroll
    for (int kk = 0; kk < 4; ++kk)
        aq[kk] = *(const v8s*)(Qp + (size_t)l15 * 128 + kk * 32 + q * 8);

    v4f S[9];
    #pragma unroll
    for (int i = 0; i < 9; ++i)
        #pragma unroll
        for (int r = 0; r < 4; ++r) S[i][r] = 0.f;

    #pragma unroll
    for (int i = 0; i < 9; ++i) {
        int m0 = (wave * 9 + i) * 16;
        #pragma unroll
        for (int kk = 0; kk < 4; ++kk) {
            v8s b = *(const v8s*)(Kp + ((size_t)(m0 + l15)) * 128 + kk * 32 + q * 8);
            S[i] = __builtin_amdgcn_mfma_f32_16x16x32_bf16(aq[kk], b, S[i], 0, 0, 0);
        }
    }

    float mx[4];
    #pragma unroll
    for (int r = 0; r < 4; ++r) {
        float m = S[0][r];
        #pragma unroll
        for (int i = 1; i < 9; ++i) m = fmaxf(m, S[i][r]);
        #pragma unroll
        for (int off = 1; off < 16; off <<= 1) m = fmaxf(m, __shfl_xor(m, off));
        mx[r] = m;
    }
    if (l15 == 0) {
        #pragma unroll
        for (int r = 0; r < 4; ++r) redmx[wave][q * 4 + r] = mx[r];
    }
    __syncthreads();
    float sum[4];
    #pragma unroll
    for (int r = 0; r < 4; ++r) {
        float g = fmaxf(fmaxf(redmx[0][q * 4 + r], redmx[1][q * 4 + r]),
                        fmaxf(redmx[2][q * 4 + r], redmx[3][q * 4 + r]));
        float s = 0.f;
        #pragma unroll
        for (int i = 0; i < 9; ++i) { float e = __expf(S[i][r] - g); S[i][r] = e; s += e; }
        #pragma unroll
        for (int off = 1; off < 16; off <<= 1) s += __shfl_xor(s, off);
        sum[r] = s;
    }
    if (l15 == 0) {
        #pragma unroll
        for (int r = 0; r < 4; ++r) redsm[wave][q * 4 + r] = sum[r];
    }
    #pragma unroll
    for (int i = 0; i < 9; ++i) {
        int m = (wave * 9 + i) * 16 + l15;
        int cm = m >> 3, mo = m & 7;
        #pragma unroll
        for (int r = 0; r < 4; ++r) {
            int n = q * 4 + r;
            P[n * 576 + ((cm ^ (n & 7)) << 3) + mo] = f2bf(S[i][r]);
        }
    }
    __syncthreads();
    float inv[4];
    #pragma unroll
    for (int r = 0; r < 4; ++r)
        inv[r] = 1.f / (redsm[0][q * 4 + r] + redsm[1][q * 4 + r] +
                        redsm[2][q * 4 + r] + redsm[3][q * 4 + r]);

    v4f o[2];
    #pragma unroll
    for (int ct = 0; ct < 2; ++ct)
        #pragma unroll
        for (int r = 0; r < 4; ++r) o[ct][r] = 0.f;

    for (int s = 0; s < 18; ++s) {
        int cm = s * 4 + q;
        v8s a = *(const v8s*)&P[l15 * 576 + ((cm ^ (l15 & 7)) << 3)];
        #pragma unroll
        for (int ct = 0; ct < 2; ++ct) {
            int c = (wave * 2 + ct) * 16 + l15;
            v8s b = *(const v8s*)(Vp + (size_t)c * 576 + s * 32 + q * 8);
            o[ct] = __builtin_amdgcn_mfma_f32_16x16x32_bf16(a, b, o[ct], 0, 0, 0);
        }
    }

    #pragma unroll
    for (int ct = 0; ct < 2; ++ct) {
        int c = (wave * 2 + ct) * 16 + l15;
        size_t base = ((size_t)p * 128 + c) * 576 + n0 + q * 4;
        if (MODE == 0) {
            float al = alpha[0];
            #pragma unroll
            for (int r = 0; r < 4; ++r)
                Of[base + r] = al * o[ct][r] * inv[r] + addsrc[base + r];
        } else {
            #pragma unroll
            for (int r = 0; r < 4; ++r)
                Oh[base + r] = f2bf(o[ct][r] * inv[r]);
        }
    }
}

// ------------------------------------- window sums for analytic gate-conv mean
__global__ __launch_bounds__(64) void wsum_kernel(
    const unsigned short* __restrict__ mji, float* __restrict__ wsum)
{
    int pair = blockIdx.x, ci = blockIdx.y, lane = threadIdx.x;
    const unsigned short* p = mji + ((size_t)pair * C_ + ci) * N_;
    float T=0, R0=0, R23=0, Cl=0, Cr=0, c00=0, c0w=0, ch0=0, chw=0;
    for (int i = lane; i < N_; i += 64) {
        float v = bf2f(p[i]);
        int r = i / 24, cc = i % 24;
        T += v;
        if (r == 0)  R0  += v;
        if (r == 23) R23 += v;
        if (cc == 0)  Cl += v;
        if (cc == 23) Cr += v;
        if (i == 0)   c00 = v;
        if (i == 23)  c0w = v;
        if (i == 552) ch0 = v;
        if (i == 575) chw = v;
    }
    #pragma unroll
    for (int off = 32; off > 0; off >>= 1) {
        T  += __shfl_xor(T, off);  R0 += __shfl_xor(R0, off);  R23 += __shfl_xor(R23, off);
        Cl += __shfl_xor(Cl, off); Cr += __shfl_xor(Cr, off);
        c00 += __shfl_xor(c00, off); c0w += __shfl_xor(c0w, off);
        ch0 += __shfl_xor(ch0, off); chw += __shfl_xor(chw, off);
    }
    if (lane == 0) {
        float rowsub[3] = {R23, 0.f, R0};
        float colsub[3] = {Cr,  0.f, Cl};
        float corner[9] = {chw, 0.f, ch0,  0.f, 0.f, 0.f,  c0w, 0.f, c00};
        float* o = wsum + ((size_t)pair * C_ + ci) * 9;
        #pragma unroll
        for (int ky = 0; ky < 3; ++ky)
            #pragma unroll
            for (int kx = 0; kx < 3; ++kx)
                o[ky * 3 + kx] = T - rowsub[ky] - colsub[kx] + corner[ky * 3 + kx];
    }
}

__global__ __launch_bounds__(128) void g_kernel(
    const float* __restrict__ wsum, const float* __restrict__ Wg,
    const float* __restrict__ Wgb, float* __restrict__ g)
{
    __shared__ float sw[C_ * 9];
    int pair = blockIdx.x; int co = threadIdx.x;
    for (int i = co; i < C_ * 9; i += 128) sw[i] = wsum[(size_t)pair * C_ * 9 + i];
    __syncthreads();
    const float* w = Wg + (size_t)co * C_ * 9;
    float acc = 0.f;
    for (int i = 0; i < C_ * 9; ++i) acc += w[i] * sw[i];
    float m = acc * (1.f / 576.f) + Wgb[co];
    g[pair * C_ + co] = 1.f / (1.f + __expf(-m));
}

__global__ void msg_kernel(
    const float* __restrict__ eii, const unsigned short* __restrict__ mji,
    const float* __restrict__ g, const float* __restrict__ bn_gamma,
    const float* __restrict__ bn_beta, const float* __restrict__ intra_w,
    const float* __restrict__ inter_w, float* __restrict__ msg)
{
    int e = blockIdx.x * blockDim.x + threadIdx.x;
    if (e >= SB * C_ * N_) return;
    int n = e % N_;
    int c = (e / N_) % C_;
    int img = e / (N_ * C_);
    int s = img >> 1, b = img & 1;
    float scale = bn_gamma[c] * rsqrtf(1.f + 1e-5f);
    float acc = 0.f;
    #pragma unroll
    for (int jj = 0; jj < 4; ++jj) {
        int pidx = (s * 4 + jj) * 2 + b;
        acc += g[pidx * C_ + c] * bf2f(mji[((size_t)pidx * C_ + c) * N_ + n]);
    }
    float inter = scale * acc + 4.f * bn_beta[c];
    msg[e] = intra_w[0] * eii[e] + inter_w[0] * inter;
}

// update: z from 4 partial planes, hhat from 2 partial planes (+bias, activations)
__global__ void update_kernel(const float* __restrict__ zrp, const float* __restrict__ zrb,
                              const float* __restrict__ hhp, const float* __restrict__ ghb,
                              const float* __restrict__ h, float* __restrict__ out)
{
    const size_t ZP = (size_t)SB * C2 * N_;
    const size_t HP = (size_t)SB * C_ * N_;
    int e = blockIdx.x * blockDim.x + threadIdx.x;
    if (e >= SB * C_ * N_) return;
    int n = e % N_;
    int c = (e / N_) % C_;
    int img = e / (N_ * C_);
    size_t zi = ((size_t)img * C2 + c) * N_ + n;
    float za = zrb[c];
    #pragma unroll
    for (int k = 0; k < 4; ++k) za += zrp[k * ZP + zi];
    float z = 1.f / (1.f + __expf(-za));
    size_t hi = ((size_t)img * C_ + c) * N_ + n;
    float ha = ghb[c] + hhp[hi] + hhp[HP + hi];
    float hh = tanhf(ha);
    out[e] = (2.f - z) * h[e] + z * hh;
}

// ------------------------------------------------------------------- launcher
extern "C" void kernel_launch(void* const* d_in, const int* in_sizes, int n_in,
                              void* d_out, int out_size, void* d_ws, size_t ws_size,
                              hipStream_t stream)
{
    const float* x      = (const float*)d_in[0];
    const float* Wf_w   = (const float*)d_in[1];
    const float* Wf_b   = (const float*)d_in[2];
    const float* Wh_w   = (const float*)d_in[3];
    const float* Wh_b   = (const float*)d_in[4];
    const float* Wl_w   = (const float*)d_in[5];
    const float* Wl_b   = (const float*)d_in[6];
    const float* alpha  = (const float*)d_in[7];
    const float* Wc     = (const float*)d_in[8];
    const float* Wg_w   = (const float*)d_in[9];
    const float* Wg_b   = (const float*)d_in[10];
    const float* bng    = (const float*)d_in[11];
    const float* bnb    = (const float*)d_in[12];
    const float* zr_w   = (const float*)d_in[13];
    const float* zr_b   = (const float*)d_in[14];
    const float* gh_w   = (const float*)d_in[15];
    const float* gh_b   = (const float*)d_in[16];
    const float* intraw = (const float*)d_in[17];
    const float* interw = (const float*)d_in[18];
    float* outp = (float*)d_out;

    float* f = (float*)d_ws;
    const size_t SZ = (size_t)SB * C_ * N_;
    float* hbuf  = f; f += SZ;
    float* eii   = f; f += SZ;                       // msg written in-place
    float* zrp   = f; f += 4 * (size_t)SB * C2 * N_; // 4 partial planes
    float* hhp   = f; f += 2 * SZ;                   // 2 partial planes
    float* wsumb = f; f += (size_t)NPAIR * C_ * 9;
    float* gbuf  = f; f += (size_t)NPAIR * C_;
    unsigned short* us = (unsigned short*)f;
    unsigned short* mji16  = us; us += (size_t)NPAIR * C_ * N_;
    unsigned short* hT16   = us; us += SZ;
    unsigned short* hc16   = us; us += SZ;           // also reused as rhbT16
    unsigned short* msgT16 = us; us += SZ;
    unsigned short* ftT    = us; us += SZ;           // also reused as ytT
    unsigned short* htT    = us; us += SZ;
    unsigned short* lt16   = us; us += SZ;
    unsigned short* Wp3    = us; us += (size_t)384 * 1152;
    unsigned short* Wpzr   = us; us += (size_t)256 * 6400;
    unsigned short* Wph    = us; us += (size_t)128 * 6400;
    unsigned short* Wcb    = us; us += (size_t)128 * 128;

    unsigned short* ytT    = ftT;
    unsigned short* rhbT16 = hc16;

    const int NELEM = SB * C_ * N_;
    dim3 eb((NELEM + 255) / 256);

    pack3_kernel<<<(384 * 1152 + 255) / 256, 256, 0, stream>>>(Wf_w, Wh_w, Wl_w, Wp3);
    pack5_kernel<<<(256 * 6400 + 255) / 256, 256, 0, stream>>>(zr_w, Wpzr, 256);
    pack5_kernel<<<(128 * 6400 + 255) / 256, 256, 0, stream>>>(gh_w, Wph, 128);
    packWc_kernel<<<64, 256, 0, stream>>>(Wc, Wcb);

    const float* hcur = x;
    for (int it = 0; it < 3; ++it) {
        float* hout = (it == 2) ? outp : hbuf;
        float* msg = eii;

        tc_kernel<<<dim3(9, SB), 256, 0, stream>>>(hcur, nullptr, nullptr, hT16, hc16);
        conv_mfma<9, 1, 1, 0><<<dim3(3, 9, SB), 256, 0, stream>>>(
            hT16, hT16, Wp3, 384, Wf_b, Wh_b, Wl_b, nullptr, ftT, htT, lt16);
        attn_mfma<0><<<dim3(36, SB), 256, 0, stream>>>(ftT, htT, lt16, eii, nullptr, hcur, alpha);
        yt_mfma<<<dim3(36, SB), 256, 0, stream>>>(hT16, Wcb, ytT);
        attn_mfma<1><<<dim3(36, NPAIR), 256, 0, stream>>>(hT16, ytT, hc16, nullptr, mji16, nullptr, nullptr);
        wsum_kernel<<<dim3(NPAIR, C_), 64, 0, stream>>>(mji16, wsumb);
        g_kernel<<<NPAIR, 128, 0, stream>>>(wsumb, Wg_w, Wg_b, gbuf);
        msg_kernel<<<eb, 256, 0, stream>>>(eii, mji16, gbuf, bng, bnb, intraw, interw, msg);
        tc_kernel<<<dim3(9, SB), 256, 0, stream>>>(msg, nullptr, nullptr, msgT16, nullptr);
        conv_mfma<25, 2, 4, 1><<<dim3(8, 9, SB), 256, 0, stream>>>(
            msgT16, hT16, Wpzr, 256, nullptr, nullptr, nullptr, zrp, nullptr, nullptr, nullptr);
        tc_kernel<<<dim3(9, SB), 256, 0, stream>>>(hcur, zrp, zr_b, rhbT16, nullptr);
        conv_mfma<25, 2, 2, 1><<<dim3(2, 9, SB), 256, 0, stream>>>(
            msgT16, rhbT16, Wph, 128, nullptr, nullptr, nullptr, hhp, nullptr, nullptr, nullptr);
        update_kernel<<<eb, 256, 0, stream>>>(zrp, zr_b, hhp, gh_b, hcur, hout);
        hcur = hout;
    }
}

// Round 8
// 1177.144 us; speedup vs baseline: 1.0478x; 1.0478x over previous
//
#include <hip/hip_runtime.h>
#include <math.h>

#define S_  5
#define B_  2
#define C_  128
#define N_  576
#define SB  10
#define NPAIR 40
#define C2  256

typedef short v8s __attribute__((ext_vector_type(8)));
typedef float v4f __attribute__((ext_vector_type(4)));

#define GLOBAL_AS __attribute__((address_space(1)))
#define LDS_AS    __attribute__((address_space(3)))

__device__ __forceinline__ unsigned short f2bf(float f) {
    union { float f; unsigned u; } v; v.f = f;
    unsigned r = (v.u + 0x7FFF + ((v.u >> 16) & 1)) >> 16;
    return (unsigned short)r;
}
__device__ __forceinline__ float bf2f(unsigned short h) {
    union { unsigned u; float f; } v; v.u = ((unsigned)h) << 16;
    return v.f;
}

// ------------------------------------------------------------------ weight packs
__global__ void pack3_kernel(const float* __restrict__ wf, const float* __restrict__ wh,
                             const float* __restrict__ wl, unsigned short* __restrict__ Wp3)
{
    int idx = blockIdx.x * 256 + threadIdx.x;
    if (idx >= 384 * 1152) return;
    int co = idx / 1152, k = idx % 1152;
    int tap = k >> 7, ci = k & 127;
    const float* w = (co < 128) ? wf : (co < 256) ? wh : wl;
    int c = co & 127;
    Wp3[idx] = f2bf(w[((size_t)c * 128 + ci) * 9 + tap]);
}
__global__ void pack5_kernel(const float* __restrict__ w, unsigned short* __restrict__ Wp, int M)
{
    int idx = blockIdx.x * 256 + threadIdx.x;
    if (idx >= M * 6400) return;
    int co = idx / 6400, k = idx % 6400;
    int tap = k >> 8, ci = k & 255;
    Wp[idx] = f2bf(w[((size_t)co * 256 + ci) * 25 + tap]);
}
__global__ void packWc_kernel(const float* __restrict__ w, unsigned short* __restrict__ o)
{
    int idx = blockIdx.x * 256 + threadIdx.x;
    if (idx < 128 * 128) o[idx] = f2bf(w[idx]);
}

// ---------------------------------------------- transpose-cast: [c][px] f32 -> [px][c] bf16
// zrp != null: multiply by r = sigmoid(sum_k zrp[k][128+c] + zrb[128+c])  (4 partial planes)
__global__ __launch_bounds__(256) void tc_kernel(
    const float* __restrict__ src, const float* __restrict__ zrp,
    const float* __restrict__ zrb,
    unsigned short* __restrict__ dst, unsigned short* __restrict__ dst2)
{
    const size_t PLANE = (size_t)SB * C2 * N_;
    __shared__ float tile[128][65];
    int img = blockIdx.y, px0 = blockIdx.x * 64, t = threadIdx.x;
    #pragma unroll
    for (int i = 0; i < 32; ++i) {
        int e = i * 256 + t; int ci = e >> 6; int px = e & 63;
        float v = src[((size_t)img * 128 + ci) * 576 + px0 + px];
        if (zrp) {
            size_t zi = ((size_t)img * C2 + 128 + ci) * 576 + px0 + px;
            float a = zrb[128 + ci];
            #pragma unroll
            for (int k = 0; k < 4; ++k) a += zrp[k * PLANE + zi];
            v *= 1.f / (1.f + __expf(-a));
        }
        tile[ci][px] = v;
        if (dst2) dst2[((size_t)img * 128 + ci) * 576 + px0 + px] = f2bf(v);
    }
    __syncthreads();
    #pragma unroll
    for (int i = 0; i < 32; ++i) {
        int e = i * 256 + t; int px = e >> 7; int ci = e & 127;
        dst[((size_t)img * 576 + px0 + px) * 128 + ci] = f2bf(tile[ci][px]);
    }
}

// ------------------------------------------------------ MFMA implicit-GEMM conv v5
// block tile: 128co x 64px, 4 waves (wave = 64co x 32px)
// ALL NCH chunk-windows staged into LDS up-front via global_load_lds, ONE barrier,
// then the whole tap loop runs with zero glds in flight (ds_reads need no vmcnt —
// this was the r5/r7 serializer: glds-vs-ds_read aliasing forced vmcnt(0) per tap).
// A weights: direct-global DEPTH-slot register ring (DEPTH | TAPS).
template<int TAPS, int R, int SPLITK, int MODE>
__global__ __launch_bounds__(256, 1) void conv_mfma(
    const unsigned short* __restrict__ srcA, const unsigned short* __restrict__ srcB,
    const unsigned short* __restrict__ Wp, int COUT,
    const float* __restrict__ b0, const float* __restrict__ b1, const float* __restrict__ b2,
    float* __restrict__ po,
    unsigned short* __restrict__ t0, unsigned short* __restrict__ t1,
    unsigned short* __restrict__ t2)
{
    constexpr int KD     = 2 * R + 1;
    constexpr int WR     = 4 + 2 * R;
    constexpr int WC     = 24 + 2 * R;
    constexpr int NPOS   = WR * WC;
    constexpr int NSLOT  = NPOS * 4;                    // 16B slots per chunk
    constexpr int CINT   = (SPLITK == 1) ? 128 : 256;   // total input channels
    constexpr int PART   = CINT / SPLITK;               // channels per K-part
    constexpr int NCH    = PART / 32;                   // 32-ci chunks per part
    constexpr int KTOT   = TAPS * CINT;
    constexpr int DEPTH  = (TAPS == 25) ? 5 : 3;        // divides TAPS
    constexpr int ROUNDS = (NSLOT + 255) / 256;
    __shared__ __align__(16) unsigned short Xs[NCH * NPOS * 32];

    int f   = blockIdx.x;
    int kk  = f % SPLITK;
    int cgb = f / SPLITK;
    int pxb = blockIdx.y;
    int img = blockIdx.z;
    int t = threadIdx.x;
    int wave = t >> 6, lane = t & 63;
    int quad = lane >> 4, l15 = lane & 15;
    int cgw = wave & 1, pgw = wave >> 1;
    int px0w = pxb * 64 + pgw * 32;
    int r0 = (pxb * 64) / 24;

    const int cibase = kk * PART;
    const unsigned short* src = (cibase >= 128) ? srcB : srcA;
    const int cioff = cibase & 127;
    const unsigned short* srcI = src + (size_t)img * 576 * 128;

    int posBase[2], pxs[2];
    #pragma unroll
    for (int s = 0; s < 2; ++s) {
        int px = px0w + s * 16 + l15;
        pxs[s] = px;
        int pr = px / 24, pc = px % 24;
        posBase[s] = (pr - r0 + R) * WC + pc + R;
    }

    const unsigned short* wRow = Wp + (size_t)(cgb * 128 + cgw * 64 + l15) * KTOT
                                 + cibase + quad * 8;

    // staging geometry precompute (per-lane global offset + validity per round)
    int goff[ROUNDS]; bool gok[ROUNDS];
    #pragma unroll
    for (int rr = 0; rr < ROUNDS; ++rr) {
        int idx = rr * 256 + wave * 64 + lane;
        int pos = idx >> 2, slot = idx & 3;
        int gr = slot ^ ((pos >> 1) & 3);
        int wr = pos / WC, wc = pos % WC;
        int grow = r0 - R + wr, gcol = wc - R;
        gok[rr] = (idx < NSLOT) && grow >= 0 && grow < 24 && gcol >= 0 && gcol < 24;
        goff[rr] = (grow * 24 + gcol) * 128 + gr * 8;
    }

    // zero everything (boundary slots keep zero), then ONE glds epoch, then barrier
    {
        v8s zv;
        #pragma unroll
        for (int j = 0; j < 8; ++j) zv[j] = 0;
        for (int i = t; i < NCH * NPOS * 4; i += 256) ((v8s*)Xs)[i] = zv;
    }
    __syncthreads();

    {
        char* lbase = (char*)&Xs[0];
        #pragma unroll
        for (int ch = 0; ch < NCH; ++ch) {
            const unsigned short* sp = srcI + cioff + ch * 32;
            #pragma unroll
            for (int rr = 0; rr < ROUNDS; ++rr) {
                if (gok[rr]) {
                    __builtin_amdgcn_global_load_lds(
                        (const GLOBAL_AS void*)(sp + goff[rr]),
                        (LDS_AS void*)(lbase + (size_t)(ch * NSLOT + rr * 256 + wave * 64) * 16),
                        16, 0, 0);
                }
            }
        }
    }

    v8s abuf[DEPTH][4];
    auto loadA = [&](int ch, int tap, int slot) {
        const unsigned short* p = wRow + ch * 32 + tap * CINT;
        #pragma unroll
        for (int c = 0; c < 4; ++c)
            abuf[slot][c] = *(const v8s*)(p + (size_t)c * 16 * KTOT);
    };

    v4f acc[4][2];
    #pragma unroll
    for (int c = 0; c < 4; ++c)
        #pragma unroll
        for (int s = 0; s < 2; ++s)
            #pragma unroll
            for (int r = 0; r < 4; ++r) acc[c][s][r] = 0.f;

    __syncthreads();   // drains ALL staging glds; no glds in flight below

    #pragma unroll
    for (int d = 0; d < DEPTH; ++d) loadA(0, d, d);

    #pragma unroll 1
    for (int ch = 0; ch < NCH; ++ch) {
        const unsigned short* XsBuf = &Xs[ch * NPOS * 32];
        const int chn = (ch + 1 < NCH) ? ch + 1 : ch;   // clamped prefetch target

        #pragma unroll
        for (int tap = 0; tap < TAPS; ++tap) {
            const int slot = tap % DEPTH;               // consistent: DEPTH | TAPS
            const int dy = tap / KD - R, dx = tap % KD - R;
            const int doff = dy * WC + dx;
            v8s bfr[2];
            #pragma unroll
            for (int s = 0; s < 2; ++s) {
                int pos = posBase[s] + doff;
                bfr[s] = *(const v8s*)&XsBuf[pos * 32 + ((quad ^ ((pos >> 1) & 3)) << 3)];
            }
            #pragma unroll
            for (int c = 0; c < 4; ++c)
                #pragma unroll
                for (int s = 0; s < 2; ++s)
                    acc[c][s] = __builtin_amdgcn_mfma_f32_16x16x32_bf16(abuf[slot][c], bfr[s], acc[c][s], 0, 0, 0);
            // ring prefetch (slot just consumed); (tap+DEPTH)%DEPTH == slot
            if (tap + DEPTH < TAPS) loadA(ch, tap + DEPTH, slot);
            else                    loadA(chn, tap + DEPTH - TAPS, slot);
        }
    }

    if (MODE == 1) {
        float* out = po + (size_t)kk * ((size_t)SB * COUT * 576)
                   + ((size_t)img * COUT + cgb * 128) * 576;
        #pragma unroll
        for (int c = 0; c < 4; ++c)
            #pragma unroll
            for (int s = 0; s < 2; ++s)
                #pragma unroll
                for (int r = 0; r < 4; ++r) {
                    int col = cgw * 64 + c * 16 + quad * 4 + r;
                    out[(size_t)col * 576 + pxs[s]] = acc[c][s][r];
                }
    } else {
        const float* bp = (cgb == 0) ? b0 : (cgb == 1) ? b1 : b2;
        #pragma unroll
        for (int c = 0; c < 4; ++c)
            #pragma unroll
            for (int s = 0; s < 2; ++s)
                #pragma unroll
                for (int r = 0; r < 4; ++r) {
                    int col = cgw * 64 + c * 16 + quad * 4 + r;
                    float v = acc[c][s][r] + bp[col];
                    if (cgb == 0)      t0[((size_t)img * 576 + pxs[s]) * 128 + col] = f2bf(v);
                    else if (cgb == 1) t1[((size_t)img * 576 + pxs[s]) * 128 + col] = f2bf(v);
                    else               t2[((size_t)img * 128 + col) * 576 + pxs[s]] = f2bf(v);
                }
    }
}

// ---------------------------------------------------------------- yt (MFMA)
__global__ __launch_bounds__(256) void yt_mfma(
    const unsigned short* __restrict__ hT, const unsigned short* __restrict__ Wcb,
    unsigned short* __restrict__ ytT)
{
    int t = threadIdx.x, wave = t >> 6, lane = t & 63;
    int q = lane >> 4, l15 = lane & 15;
    int n0 = blockIdx.x * 16, img = blockIdx.y;
    v4f acc[2];
    #pragma unroll
    for (int ct = 0; ct < 2; ++ct)
        #pragma unroll
        for (int r = 0; r < 4; ++r) acc[ct][r] = 0.f;
    #pragma unroll
    for (int kk = 0; kk < 4; ++kk) {
        v8s b = *(const v8s*)(hT + ((size_t)img * 576 + n0 + l15) * 128 + kk * 32 + q * 8);
        #pragma unroll
        for (int ct = 0; ct < 2; ++ct) {
            v8s a = *(const v8s*)(Wcb + (size_t)((wave * 2 + ct) * 16 + l15) * 128 + kk * 32 + q * 8);
            acc[ct] = __builtin_amdgcn_mfma_f32_16x16x32_bf16(a, b, acc[ct], 0, 0, 0);
        }
    }
    #pragma unroll
    for (int ct = 0; ct < 2; ++ct) {
        unsigned short* op = ytT + ((size_t)img * 576 + n0 + l15) * 128 + (wave * 2 + ct) * 16 + q * 4;
        #pragma unroll
        for (int r = 0; r < 4; ++r) op[r] = f2bf(acc[ct][r]);
    }
}

// ---------------------------------------------------- MFMA flash attention
template<int MODE>
__global__ __launch_bounds__(256) void attn_mfma(
    const unsigned short* __restrict__ QT, const unsigned short* __restrict__ KT,
    const unsigned short* __restrict__ Vc, float* __restrict__ Of,
    unsigned short* __restrict__ Oh, const float* __restrict__ addsrc,
    const float* __restrict__ alpha)
{
    __shared__ __align__(16) unsigned short P[16 * 576];
    __shared__ float redmx[4][16];
    __shared__ float redsm[4][16];
    int t = threadIdx.x;
    int wave = t >> 6, lane = t & 63;
    int q = lane >> 4, l15 = lane & 15;
    int n0 = blockIdx.x * 16;
    int p = blockIdx.y;
    int qimg, kimg;
    if (MODE == 0) { qimg = p; kimg = p; }
    else {
        int b = p & 1; int ij = p >> 1; int i = ij >> 2; int jj = ij & 3;
        int j = jj + (jj >= i ? 1 : 0);
        qimg = i * 2 + b; kimg = j * 2 + b;
    }
    const unsigned short* Qp = QT + ((size_t)qimg * 576 + n0) * 128;
    const unsigned short* Kp = KT + (size_t)kimg * 576 * 128;
    const unsigned short* Vp = Vc + (size_t)kimg * 128 * 576;

    v8s aq[4];
    #pragma unroll
    for (int kk = 0; kk < 4; ++kk)
        aq[kk] = *(const v8s*)(Qp + (size_t)l15 * 128 + kk * 32 + q * 8);

    v4f S[9];
    #pragma unroll
    for (int i = 0; i < 9; ++i)
        #pragma unroll
        for (int r = 0; r < 4; ++r) S[i][r] = 0.f;

    #pragma unroll
    for (int i = 0; i < 9; ++i) {
        int m0 = (wave * 9 + i) * 16;
        #pragma unroll
        for (int kk = 0; kk < 4; ++kk) {
            v8s b = *(const v8s*)(Kp + ((size_t)(m0 + l15)) * 128 + kk * 32 + q * 8);
            S[i] = __builtin_amdgcn_mfma_f32_16x16x32_bf16(aq[kk], b, S[i], 0, 0, 0);
        }
    }

    float mx[4];
    #pragma unroll
    for (int r = 0; r < 4; ++r) {
        float m = S[0][r];
        #pragma unroll
        for (int i = 1; i < 9; ++i) m = fmaxf(m, S[i][r]);
        #pragma unroll
        for (int off = 1; off < 16; off <<= 1) m = fmaxf(m, __shfl_xor(m, off));
        mx[r] = m;
    }
    if (l15 == 0) {
        #pragma unroll
        for (int r = 0; r < 4; ++r) redmx[wave][q * 4 + r] = mx[r];
    }
    __syncthreads();
    float sum[4];
    #pragma unroll
    for (int r = 0; r < 4; ++r) {
        float g = fmaxf(fmaxf(redmx[0][q * 4 + r], redmx[1][q * 4 + r]),
                        fmaxf(redmx[2][q * 4 + r], redmx[3][q * 4 + r]));
        float s = 0.f;
        #pragma unroll
        for (int i = 0; i < 9; ++i) { float e = __expf(S[i][r] - g); S[i][r] = e; s += e; }
        #pragma unroll
        for (int off = 1; off < 16; off <<= 1) s += __shfl_xor(s, off);
        sum[r] = s;
    }
    if (l15 == 0) {
        #pragma unroll
        for (int r = 0; r < 4; ++r) redsm[wave][q * 4 + r] = sum[r];
    }
    #pragma unroll
    for (int i = 0; i < 9; ++i) {
        int m = (wave * 9 + i) * 16 + l15;
        int cm = m >> 3, mo = m & 7;
        #pragma unroll
        for (int r = 0; r < 4; ++r) {
            int n = q * 4 + r;
            P[n * 576 + ((cm ^ (n & 7)) << 3) + mo] = f2bf(S[i][r]);
        }
    }
    __syncthreads();
    float inv[4];
    #pragma unroll
    for (int r = 0; r < 4; ++r)
        inv[r] = 1.f / (redsm[0][q * 4 + r] + redsm[1][q * 4 + r] +
                        redsm[2][q * 4 + r] + redsm[3][q * 4 + r]);

    v4f o[2];
    #pragma unroll
    for (int ct = 0; ct < 2; ++ct)
        #pragma unroll
        for (int r = 0; r < 4; ++r) o[ct][r] = 0.f;

    for (int s = 0; s < 18; ++s) {
        int cm = s * 4 + q;
        v8s a = *(const v8s*)&P[l15 * 576 + ((cm ^ (l15 & 7)) << 3)];
        #pragma unroll
        for (int ct = 0; ct < 2; ++ct) {
            int c = (wave * 2 + ct) * 16 + l15;
            v8s b = *(const v8s*)(Vp + (size_t)c * 576 + s * 32 + q * 8);
            o[ct] = __builtin_amdgcn_mfma_f32_16x16x32_bf16(a, b, o[ct], 0, 0, 0);
        }
    }

    #pragma unroll
    for (int ct = 0; ct < 2; ++ct) {
        int c = (wave * 2 + ct) * 16 + l15;
        size_t base = ((size_t)p * 128 + c) * 576 + n0 + q * 4;
        if (MODE == 0) {
            float al = alpha[0];
            #pragma unroll
            for (int r = 0; r < 4; ++r)
                Of[base + r] = al * o[ct][r] * inv[r] + addsrc[base + r];
        } else {
            #pragma unroll
            for (int r = 0; r < 4; ++r)
                Oh[base + r] = f2bf(o[ct][r] * inv[r]);
        }
    }
}

// ------------------------------------- window sums for analytic gate-conv mean
__global__ __launch_bounds__(64) void wsum_kernel(
    const unsigned short* __restrict__ mji, float* __restrict__ wsum)
{
    int pair = blockIdx.x, ci = blockIdx.y, lane = threadIdx.x;
    const unsigned short* p = mji + ((size_t)pair * C_ + ci) * N_;
    float T=0, R0=0, R23=0, Cl=0, Cr=0, c00=0, c0w=0, ch0=0, chw=0;
    for (int i = lane; i < N_; i += 64) {
        float v = bf2f(p[i]);
        int r = i / 24, cc = i % 24;
        T += v;
        if (r == 0)  R0  += v;
        if (r == 23) R23 += v;
        if (cc == 0)  Cl += v;
        if (cc == 23) Cr += v;
        if (i == 0)   c00 = v;
        if (i == 23)  c0w = v;
        if (i == 552) ch0 = v;
        if (i == 575) chw = v;
    }
    #pragma unroll
    for (int off = 32; off > 0; off >>= 1) {
        T  += __shfl_xor(T, off);  R0 += __shfl_xor(R0, off);  R23 += __shfl_xor(R23, off);
        Cl += __shfl_xor(Cl, off); Cr += __shfl_xor(Cr, off);
        c00 += __shfl_xor(c00, off); c0w += __shfl_xor(c0w, off);
        ch0 += __shfl_xor(ch0, off); chw += __shfl_xor(chw, off);
    }
    if (lane == 0) {
        float rowsub[3] = {R23, 0.f, R0};
        float colsub[3] = {Cr,  0.f, Cl};
        float corner[9] = {chw, 0.f, ch0,  0.f, 0.f, 0.f,  c0w, 0.f, c00};
        float* o = wsum + ((size_t)pair * C_ + ci) * 9;
        #pragma unroll
        for (int ky = 0; ky < 3; ++ky)
            #pragma unroll
            for (int kx = 0; kx < 3; ++kx)
                o[ky * 3 + kx] = T - rowsub[ky] - colsub[kx] + corner[ky * 3 + kx];
    }
}

__global__ __launch_bounds__(128) void g_kernel(
    const float* __restrict__ wsum, const float* __restrict__ Wg,
    const float* __restrict__ Wgb, float* __restrict__ g)
{
    __shared__ float sw[C_ * 9];
    int pair = blockIdx.x; int co = threadIdx.x;
    for (int i = co; i < C_ * 9; i += 128) sw[i] = wsum[(size_t)pair * C_ * 9 + i];
    __syncthreads();
    const float* w = Wg + (size_t)co * C_ * 9;
    float acc = 0.f;
    for (int i = 0; i < C_ * 9; ++i) acc += w[i] * sw[i];
    float m = acc * (1.f / 576.f) + Wgb[co];
    g[pair * C_ + co] = 1.f / (1.f + __expf(-m));
}

__global__ void msg_kernel(
    const float* __restrict__ eii, const unsigned short* __restrict__ mji,
    const float* __restrict__ g, const float* __restrict__ bn_gamma,
    const float* __restrict__ bn_beta, const float* __restrict__ intra_w,
    const float* __restrict__ inter_w, float* __restrict__ msg)
{
    int e = blockIdx.x * blockDim.x + threadIdx.x;
    if (e >= SB * C_ * N_) return;
    int n = e % N_;
    int c = (e / N_) % C_;
    int img = e / (N_ * C_);
    int s = img >> 1, b = img & 1;
    float scale = bn_gamma[c] * rsqrtf(1.f + 1e-5f);
    float acc = 0.f;
    #pragma unroll
    for (int jj = 0; jj < 4; ++jj) {
        int pidx = (s * 4 + jj) * 2 + b;
        acc += g[pidx * C_ + c] * bf2f(mji[((size_t)pidx * C_ + c) * N_ + n]);
    }
    float inter = scale * acc + 4.f * bn_beta[c];
    msg[e] = intra_w[0] * eii[e] + inter_w[0] * inter;
}

// update: z from 4 partial planes, hhat from 2 partial planes (+bias, activations)
__global__ void update_kernel(const float* __restrict__ zrp, const float* __restrict__ zrb,
                              const float* __restrict__ hhp, const float* __restrict__ ghb,
                              const float* __restrict__ h, float* __restrict__ out)
{
    const size_t ZP = (size_t)SB * C2 * N_;
    const size_t HP = (size_t)SB * C_ * N_;
    int e = blockIdx.x * blockDim.x + threadIdx.x;
    if (e >= SB * C_ * N_) return;
    int n = e % N_;
    int c = (e / N_) % C_;
    int img = e / (N_ * C_);
    size_t zi = ((size_t)img * C2 + c) * N_ + n;
    float za = zrb[c];
    #pragma unroll
    for (int k = 0; k < 4; ++k) za += zrp[k * ZP + zi];
    float z = 1.f / (1.f + __expf(-za));
    size_t hi = ((size_t)img * C_ + c) * N_ + n;
    float ha = ghb[c] + hhp[hi] + hhp[HP + hi];
    float hh = tanhf(ha);
    out[e] = (2.f - z) * h[e] + z * hh;
}

// ------------------------------------------------------------------- launcher
extern "C" void kernel_launch(void* const* d_in, const int* in_sizes, int n_in,
                              void* d_out, int out_size, void* d_ws, size_t ws_size,
                              hipStream_t stream)
{
    const float* x      = (const float*)d_in[0];
    const float* Wf_w   = (const float*)d_in[1];
    const float* Wf_b   = (const float*)d_in[2];
    const float* Wh_w   = (const float*)d_in[3];
    const float* Wh_b   = (const float*)d_in[4];
    const float* Wl_w   = (const float*)d_in[5];
    const float* Wl_b   = (const float*)d_in[6];
    const float* alpha  = (const float*)d_in[7];
    const float* Wc     = (const float*)d_in[8];
    const float* Wg_w   = (const float*)d_in[9];
    const float* Wg_b   = (const float*)d_in[10];
    const float* bng    = (const float*)d_in[11];
    const float* bnb    = (const float*)d_in[12];
    const float* zr_w   = (const float*)d_in[13];
    const float* zr_b   = (const float*)d_in[14];
    const float* gh_w   = (const float*)d_in[15];
    const float* gh_b   = (const float*)d_in[16];
    const float* intraw = (const float*)d_in[17];
    const float* interw = (const float*)d_in[18];
    float* outp = (float*)d_out;

    float* f = (float*)d_ws;
    const size_t SZ = (size_t)SB * C_ * N_;
    float* hbuf  = f; f += SZ;
    float* eii   = f; f += SZ;                       // msg written in-place
    float* zrp   = f; f += 4 * (size_t)SB * C2 * N_; // 4 partial planes
    float* hhp   = f; f += 2 * SZ;                   // 2 partial planes
    float* wsumb = f; f += (size_t)NPAIR * C_ * 9;
    float* gbuf  = f; f += (size_t)NPAIR * C_;
    unsigned short* us = (unsigned short*)f;
    unsigned short* mji16  = us; us += (size_t)NPAIR * C_ * N_;
    unsigned short* hT16   = us; us += SZ;
    unsigned short* hc16   = us; us += SZ;           // also reused as rhbT16
    unsigned short* msgT16 = us; us += SZ;
    unsigned short* ftT    = us; us += SZ;           // also reused as ytT
    unsigned short* htT    = us; us += SZ;
    unsigned short* lt16   = us; us += SZ;
    unsigned short* Wp3    = us; us += (size_t)384 * 1152;
    unsigned short* Wpzr   = us; us += (size_t)256 * 6400;
    unsigned short* Wph    = us; us += (size_t)128 * 6400;
    unsigned short* Wcb    = us; us += (size_t)128 * 128;

    unsigned short* ytT    = ftT;
    unsigned short* rhbT16 = hc16;

    const int NELEM = SB * C_ * N_;
    dim3 eb((NELEM + 255) / 256);

    pack3_kernel<<<(384 * 1152 + 255) / 256, 256, 0, stream>>>(Wf_w, Wh_w, Wl_w, Wp3);
    pack5_kernel<<<(256 * 6400 + 255) / 256, 256, 0, stream>>>(zr_w, Wpzr, 256);
    pack5_kernel<<<(128 * 6400 + 255) / 256, 256, 0, stream>>>(gh_w, Wph, 128);
    packWc_kernel<<<64, 256, 0, stream>>>(Wc, Wcb);

    const float* hcur = x;
    for (int it = 0; it < 3; ++it) {
        float* hout = (it == 2) ? outp : hbuf;
        float* msg = eii;

        tc_kernel<<<dim3(9, SB), 256, 0, stream>>>(hcur, nullptr, nullptr, hT16, hc16);
        conv_mfma<9, 1, 1, 0><<<dim3(3, 9, SB), 256, 0, stream>>>(
            hT16, hT16, Wp3, 384, Wf_b, Wh_b, Wl_b, nullptr, ftT, htT, lt16);
        attn_mfma<0><<<dim3(36, SB), 256, 0, stream>>>(ftT, htT, lt16, eii, nullptr, hcur, alpha);
        yt_mfma<<<dim3(36, SB), 256, 0, stream>>>(hT16, Wcb, ytT);
        attn_mfma<1><<<dim3(36, NPAIR), 256, 0, stream>>>(hT16, ytT, hc16, nullptr, mji16, nullptr, nullptr);
        wsum_kernel<<<dim3(NPAIR, C_), 64, 0, stream>>>(mji16, wsumb);
        g_kernel<<<NPAIR, 128, 0, stream>>>(wsumb, Wg_w, Wg_b, gbuf);
        msg_kernel<<<eb, 256, 0, stream>>>(eii, mji16, gbuf, bng, bnb, intraw, interw, msg);
        tc_kernel<<<dim3(9, SB), 256, 0, stream>>>(msg, nullptr, nullptr, msgT16, nullptr);
        conv_mfma<25, 2, 4, 1><<<dim3(8, 9, SB), 256, 0, stream>>>(
            msgT16, hT16, Wpzr, 256, nullptr, nullptr, nullptr, zrp, nullptr, nullptr, nullptr);
        tc_kernel<<<dim3(9, SB), 256, 0, stream>>>(hcur, zrp, zr_b, rhbT16, nullptr);
        conv_mfma<25, 2, 2, 1><<<dim3(2, 9, SB), 256, 0, stream>>>(
            msgT16, rhbT16, Wph, 128, nullptr, nullptr, nullptr, hhp, nullptr, nullptr, nullptr);
        update_kernel<<<eb, 256, 0, stream>>>(zrp, zr_b, hhp, gh_b, hcur, hout);
        hcur = hout;
    }
}

// Round 9
// 856.495 us; speedup vs baseline: 1.4400x; 1.3744x over previous
//
#include <hip/hip_runtime.h>
#include <math.h>

#define S_  5
#define B_  2
#define C_  128
#define N_  576
#define SB  10
#define NPAIR 40
#define C2  256

typedef short v8s __attribute__((ext_vector_type(8)));
typedef float v4f __attribute__((ext_vector_type(4)));

#define GLOBAL_AS __attribute__((address_space(1)))
#define LDS_AS    __attribute__((address_space(3)))

__device__ __forceinline__ unsigned short f2bf(float f) {
    union { float f; unsigned u; } v; v.f = f;
    unsigned r = (v.u + 0x7FFF + ((v.u >> 16) & 1)) >> 16;
    return (unsigned short)r;
}
__device__ __forceinline__ float bf2f(unsigned short h) {
    union { unsigned u; float f; } v; v.u = ((unsigned)h) << 16;
    return v.f;
}

// ------------------------------------------------------------------ weight packs
// Fragment-major A layout: [cgb][kk(SPLITK)][ch(2)][g(KD)][tap_l(KD)][c(4)][l15(16)][quad(4)][j(8)]
// co = cgb*64 + c*16 + l15 ; ci = kk*64 + ch*32 + quad*8 + j ; tap = g*KD + tap_l
__global__ void packA5_kernel(const float* __restrict__ w, unsigned short* __restrict__ Apk, int M)
{
    int idx = blockIdx.x * 256 + threadIdx.x;
    if (idx >= M * 6400) return;
    int r = idx;
    int j = r & 7;      r >>= 3;
    int quad = r & 3;   r >>= 2;
    int l15 = r & 15;   r >>= 4;
    int c = r & 3;      r >>= 2;
    int tap_l = r % 5;  r /= 5;
    int g = r % 5;      r /= 5;
    int ch = r & 1;     r >>= 1;
    int kk = r & 3;     r >>= 2;
    int cgb = r;
    int co = cgb * 64 + c * 16 + l15;
    int ci = kk * 64 + ch * 32 + quad * 8 + j;
    int tap = g * 5 + tap_l;
    Apk[idx] = f2bf(w[((size_t)co * 256 + ci) * 25 + tap]);
}
__global__ void packA3_kernel(const float* __restrict__ wf, const float* __restrict__ wh,
                              const float* __restrict__ wl, unsigned short* __restrict__ Apk)
{
    int idx = blockIdx.x * 256 + threadIdx.x;
    if (idx >= 384 * 1152) return;
    int r = idx;
    int j = r & 7;      r >>= 3;
    int quad = r & 3;   r >>= 2;
    int l15 = r & 15;   r >>= 4;
    int c = r & 3;      r >>= 2;
    int tap_l = r % 3;  r /= 3;
    int g = r % 3;      r /= 3;
    int ch = r & 1;     r >>= 1;
    int kk = r & 1;     r >>= 1;
    int cgb = r;                       // 0..5
    int co = cgb * 64 + c * 16 + l15;  // 0..383
    const float* w = (co < 128) ? wf : (co < 256) ? wh : wl;
    int cl = co & 127;
    int ci = kk * 64 + ch * 32 + quad * 8 + j;
    int tap = g * 3 + tap_l;
    Apk[idx] = f2bf(w[((size_t)cl * 128 + ci) * 9 + tap]);
}
__global__ void packWc_kernel(const float* __restrict__ w, unsigned short* __restrict__ o)
{
    int idx = blockIdx.x * 256 + threadIdx.x;
    if (idx < 128 * 128) o[idx] = f2bf(w[idx]);
}

// ---------------------------------------------- transpose-cast: [c][px] f32 -> [px][c] bf16
// zrp != null: multiply by r = sigmoid(sum_{k<4} zrp[k][128+c] + zrb[128+c])
__global__ __launch_bounds__(256) void tc_kernel(
    const float* __restrict__ src, const float* __restrict__ zrp,
    const float* __restrict__ zrb,
    unsigned short* __restrict__ dst, unsigned short* __restrict__ dst2)
{
    const size_t PLANE = (size_t)SB * C2 * N_;
    __shared__ float tile[128][65];
    int img = blockIdx.y, px0 = blockIdx.x * 64, t = threadIdx.x;
    #pragma unroll
    for (int i = 0; i < 32; ++i) {
        int e = i * 256 + t; int ci = e >> 6; int px = e & 63;
        float v = src[((size_t)img * 128 + ci) * 576 + px0 + px];
        if (zrp) {
            size_t zi = ((size_t)img * C2 + 128 + ci) * 576 + px0 + px;
            float a = zrb[128 + ci];
            #pragma unroll
            for (int k = 0; k < 4; ++k) a += zrp[k * PLANE + zi];
            v *= 1.f / (1.f + __expf(-a));
        }
        tile[ci][px] = v;
        if (dst2) dst2[((size_t)img * 128 + ci) * 576 + px0 + px] = f2bf(v);
    }
    __syncthreads();
    #pragma unroll
    for (int i = 0; i < 32; ++i) {
        int e = i * 256 + t; int px = e >> 7; int ci = e & 127;
        dst[((size_t)img * 576 + px0 + px) * 128 + ci] = f2bf(tile[ci][px]);
    }
}

// ------------------------------------------------------ MFMA implicit-GEMM conv v6
// block = 64 co x 192 px (4 waves = 4 px-slices of 48); A staged to LDS (shared by
// all waves) via linear glds from fragment-major pack; B windows per-chunk in LDS.
// K-sub = (ci-chunk 32, kernel-row): stage A(sub+1) -> compute KD taps -> barrier.
// Output: f32 partial plane per kk.
template<int KD, int R, int CINT>
__global__ __launch_bounds__(256, 1) void conv_mfma(
    const unsigned short* __restrict__ srcA, const unsigned short* __restrict__ srcB,
    const unsigned short* __restrict__ Apk, int COUT, float* __restrict__ po)
{
    constexpr int SPLITK = CINT / 64;
    constexpr int NCH    = 2;
    constexpr int NSUB   = NCH * KD;
    constexpr int WR     = 8 + 2 * R;
    constexpr int WC     = 24 + 2 * R;
    constexpr int NPOS   = WR * WC;
    constexpr int NSLOTB = NPOS * 4;
    constexpr int RB     = (NSLOTB + 255) / 256;
    constexpr int AUNITS = KD * 4 * 64;          // 16B units per A-sub
    constexpr int AR     = AUNITS / 256;
    __shared__ __align__(16) unsigned short Ab[2][AUNITS * 8];
    __shared__ __align__(16) unsigned short Bb[NPOS * 32];

    int f   = blockIdx.x;
    int kk  = f % SPLITK;
    int cgb = f / SPLITK;
    int pxb = blockIdx.y;                 // 0..2 (192 px each)
    int img = blockIdx.z;
    int t = threadIdx.x;
    int wave = t >> 6, lane = t & 63;
    int quad = lane >> 4, l15 = lane & 15;
    int r0 = pxb * 8;                     // 192/24 = 8 rows per px-block

    const int cibase = kk * 64;
    const unsigned short* src = (cibase >= 128) ? srcB : srcA;
    const int cioff0 = cibase & 127;
    const unsigned short* srcI = src + (size_t)img * 576 * 128;

    int posBase[3], pxs[3];
    #pragma unroll
    for (int s = 0; s < 3; ++s) {
        int px = pxb * 192 + wave * 48 + s * 16 + l15;
        pxs[s] = px;
        int pr = px / 24, pc = px % 24;
        posBase[s] = (pr - r0 + R) * WC + pc + R;
    }

    // B staging geometry (per-lane offset+validity per round)
    int goffB[RB]; bool gokB[RB];
    #pragma unroll
    for (int rr = 0; rr < RB; ++rr) {
        int idx = rr * 256 + wave * 64 + lane;
        int pos = idx >> 2, slotq = idx & 3;
        int gr = slotq ^ ((pos >> 1) & 3);
        int wr = pos / WC, wc = pos % WC;
        int grow = r0 - R + wr, gcol = wc - R;
        gokB[rr] = (idx < NSLOTB) && grow >= 0 && grow < 24 && gcol >= 0 && gcol < 24;
        goffB[rr] = (grow * 24 + gcol) * 128 + gr * 8;
    }

    auto stageB = [&](int ch) {
        const unsigned short* sp = srcI + cioff0 + ch * 32;
        #pragma unroll
        for (int rr = 0; rr < RB; ++rr) {
            if (gokB[rr]) {
                __builtin_amdgcn_global_load_lds(
                    (const GLOBAL_AS void*)(sp + goffB[rr]),
                    (LDS_AS void*)((char*)&Bb[0] + (size_t)(rr * 256 + wave * 64) * 16),
                    16, 0, 0);
            }
        }
    };
    auto stageA = [&](int sub, int buf) {
        const unsigned short* sp = Apk + ((size_t)((cgb * SPLITK + kk) * NSUB + sub)) * (AUNITS * 8);
        #pragma unroll
        for (int r = 0; r < AR; ++r) {
            int u0 = r * 256 + wave * 64;
            __builtin_amdgcn_global_load_lds(
                (const GLOBAL_AS void*)(sp + (size_t)(u0 + lane) * 8),
                (LDS_AS void*)((char*)&Ab[buf][0] + (size_t)u0 * 16),
                16, 0, 0);
        }
    };

    v4f acc[4][3];
    #pragma unroll
    for (int c = 0; c < 4; ++c)
        #pragma unroll
        for (int s = 0; s < 3; ++s)
            #pragma unroll
            for (int r = 0; r < 4; ++r) acc[c][s][r] = 0.f;

    // zero B (boundary slots stay zero), then first stages, barrier
    {
        v8s zv;
        #pragma unroll
        for (int j = 0; j < 8; ++j) zv[j] = 0;
        for (int i = t; i < NPOS * 4; i += 256) ((v8s*)Bb)[i] = zv;
    }
    __syncthreads();
    stageB(0);
    stageA(0, 0);
    __syncthreads();

    int sub = 0;
    #pragma unroll 1
    for (int ch = 0; ch < NCH; ++ch) {
        #pragma unroll 1
        for (int g = 0; g < KD; ++g) {
            if (sub + 1 < NSUB) stageA(sub + 1, (sub + 1) & 1);
            const unsigned short* Ap = &Ab[sub & 1][0];
            #pragma unroll
            for (int tl = 0; tl < KD; ++tl) {
                int doff = (g - R) * WC + (tl - R);
                v8s a[4];
                #pragma unroll
                for (int c = 0; c < 4; ++c)
                    a[c] = *(const v8s*)&Ap[((tl * 4 + c) * 64 + l15 * 4 + quad) * 8];
                v8s b[3];
                #pragma unroll
                for (int s = 0; s < 3; ++s) {
                    int pos = posBase[s] + doff;
                    b[s] = *(const v8s*)&Bb[pos * 32 + ((quad ^ ((pos >> 1) & 3)) << 3)];
                }
                #pragma unroll
                for (int c = 0; c < 4; ++c)
                    #pragma unroll
                    for (int s = 0; s < 3; ++s)
                        acc[c][s] = __builtin_amdgcn_mfma_f32_16x16x32_bf16(a[c], b[s], acc[c][s], 0, 0, 0);
            }
            __syncthreads();   // A(sub+1) staged & all reads of this sub done
            ++sub;
        }
        if (ch + 1 < NCH) { stageB(ch + 1); __syncthreads(); }
    }

    float* out = po + (size_t)kk * ((size_t)SB * COUT * 576)
               + ((size_t)img * COUT + cgb * 64) * 576;
    #pragma unroll
    for (int c = 0; c < 4; ++c)
        #pragma unroll
        for (int s = 0; s < 3; ++s)
            #pragma unroll
            for (int r = 0; r < 4; ++r) {
                int col = c * 16 + quad * 4 + r;
                out[(size_t)col * 576 + pxs[s]] = acc[c][s][r];
            }
}

// --------------------------------------- combine conv3 partials -> ftT/htT/lt16
__global__ __launch_bounds__(256) void combine3_kernel(
    const float* __restrict__ po3, const float* __restrict__ bf_,
    const float* __restrict__ bh_, const float* __restrict__ bl_,
    unsigned short* __restrict__ ftT, unsigned short* __restrict__ htT,
    unsigned short* __restrict__ lt16)
{
    const size_t P3 = (size_t)SB * 384 * N_;
    __shared__ float tile[128][65];
    int img = blockIdx.y, px0 = blockIdx.x * 64, t = threadIdx.x;
    #pragma unroll 1
    for (int w = 0; w < 3; ++w) {
        const float* bias = (w == 0) ? bf_ : (w == 1) ? bh_ : bl_;
        if (w) __syncthreads();
        #pragma unroll
        for (int i = 0; i < 32; ++i) {
            int e = i * 256 + t; int cl = e >> 6; int px = e & 63;
            size_t idx = ((size_t)img * 384 + w * 128 + cl) * N_ + px0 + px;
            float v = po3[idx] + po3[P3 + idx] + bias[cl];
            if (w == 2) lt16[((size_t)img * 128 + cl) * N_ + px0 + px] = f2bf(v);
            else tile[cl][px] = v;
        }
        if (w < 2) {
            __syncthreads();
            unsigned short* d = (w == 0) ? ftT : htT;
            #pragma unroll
            for (int i = 0; i < 32; ++i) {
                int e = i * 256 + t; int px = e >> 7; int cl = e & 127;
                d[((size_t)img * N_ + px0 + px) * 128 + cl] = f2bf(tile[cl][px]);
            }
        }
    }
}

// ---------------------------------------------------------------- yt (MFMA)
__global__ __launch_bounds__(256) void yt_mfma(
    const unsigned short* __restrict__ hT, const unsigned short* __restrict__ Wcb,
    unsigned short* __restrict__ ytT)
{
    int t = threadIdx.x, wave = t >> 6, lane = t & 63;
    int q = lane >> 4, l15 = lane & 15;
    int n0 = blockIdx.x * 16, img = blockIdx.y;
    v4f acc[2];
    #pragma unroll
    for (int ct = 0; ct < 2; ++ct)
        #pragma unroll
        for (int r = 0; r < 4; ++r) acc[ct][r] = 0.f;
    #pragma unroll
    for (int kk = 0; kk < 4; ++kk) {
        v8s b = *(const v8s*)(hT + ((size_t)img * 576 + n0 + l15) * 128 + kk * 32 + q * 8);
        #pragma unroll
        for (int ct = 0; ct < 2; ++ct) {
            v8s a = *(const v8s*)(Wcb + (size_t)((wave * 2 + ct) * 16 + l15) * 128 + kk * 32 + q * 8);
            acc[ct] = __builtin_amdgcn_mfma_f32_16x16x32_bf16(a, b, acc[ct], 0, 0, 0);
        }
    }
    #pragma unroll
    for (int ct = 0; ct < 2; ++ct) {
        unsigned short* op = ytT + ((size_t)img * 576 + n0 + l15) * 128 + (wave * 2 + ct) * 16 + q * 4;
        #pragma unroll
        for (int r = 0; r < 4; ++r) op[r] = f2bf(acc[ct][r]);
    }
}

// ---------------------------------------------------- MFMA flash attention
template<int MODE>
__global__ __launch_bounds__(256) void attn_mfma(
    const unsigned short* __restrict__ QT, const unsigned short* __restrict__ KT,
    const unsigned short* __restrict__ Vc, float* __restrict__ Of,
    unsigned short* __restrict__ Oh, const float* __restrict__ addsrc,
    const float* __restrict__ alpha)
{
    __shared__ __align__(16) unsigned short P[16 * 576];
    __shared__ float redmx[4][16];
    __shared__ float redsm[4][16];
    int t = threadIdx.x;
    int wave = t >> 6, lane = t & 63;
    int q = lane >> 4, l15 = lane & 15;
    int n0 = blockIdx.x * 16;
    int p = blockIdx.y;
    int qimg, kimg;
    if (MODE == 0) { qimg = p; kimg = p; }
    else {
        int b = p & 1; int ij = p >> 1; int i = ij >> 2; int jj = ij & 3;
        int j = jj + (jj >= i ? 1 : 0);
        qimg = i * 2 + b; kimg = j * 2 + b;
    }
    const unsigned short* Qp = QT + ((size_t)qimg * 576 + n0) * 128;
    const unsigned short* Kp = KT + (size_t)kimg * 576 * 128;
    const unsigned short* Vp = Vc + (size_t)kimg * 128 * 576;

    v8s aq[4];
    #pragma unroll
    for (int kk = 0; kk < 4; ++kk)
        aq[kk] = *(const v8s*)(Qp + (size_t)l15 * 128 + kk * 32 + q * 8);

    v4f S[9];
    #pragma unroll
    for (int i = 0; i < 9; ++i)
        #pragma unroll
        for (int r = 0; r < 4; ++r) S[i][r] = 0.f;

    #pragma unroll
    for (int i = 0; i < 9; ++i) {
        int m0 = (wave * 9 + i) * 16;
        #pragma unroll
        for (int kk = 0; kk < 4; ++kk) {
            v8s b = *(const v8s*)(Kp + ((size_t)(m0 + l15)) * 128 + kk * 32 + q * 8);
            S[i] = __builtin_amdgcn_mfma_f32_16x16x32_bf16(aq[kk], b, S[i], 0, 0, 0);
        }
    }

    float mx[4];
    #pragma unroll
    for (int r = 0; r < 4; ++r) {
        float m = S[0][r];
        #pragma unroll
        for (int i = 1; i < 9; ++i) m = fmaxf(m, S[i][r]);
        #pragma unroll
        for (int off = 1; off < 16; off <<= 1) m = fmaxf(m, __shfl_xor(m, off));
        mx[r] = m;
    }
    if (l15 == 0) {
        #pragma unroll
        for (int r = 0; r < 4; ++r) redmx[wave][q * 4 + r] = mx[r];
    }
    __syncthreads();
    float sum[4];
    #pragma unroll
    for (int r = 0; r < 4; ++r) {
        float g = fmaxf(fmaxf(redmx[0][q * 4 + r], redmx[1][q * 4 + r]),
                        fmaxf(redmx[2][q * 4 + r], redmx[3][q * 4 + r]));
        float s = 0.f;
        #pragma unroll
        for (int i = 0; i < 9; ++i) { float e = __expf(S[i][r] - g); S[i][r] = e; s += e; }
        #pragma unroll
        for (int off = 1; off < 16; off <<= 1) s += __shfl_xor(s, off);
        sum[r] = s;
    }
    if (l15 == 0) {
        #pragma unroll
        for (int r = 0; r < 4; ++r) redsm[wave][q * 4 + r] = sum[r];
    }
    #pragma unroll
    for (int i = 0; i < 9; ++i) {
        int m = (wave * 9 + i) * 16 + l15;
        int cm = m >> 3, mo = m & 7;
        #pragma unroll
        for (int r = 0; r < 4; ++r) {
            int n = q * 4 + r;
            P[n * 576 + ((cm ^ (n & 7)) << 3) + mo] = f2bf(S[i][r]);
        }
    }
    __syncthreads();
    float inv[4];
    #pragma unroll
    for (int r = 0; r < 4; ++r)
        inv[r] = 1.f / (redsm[0][q * 4 + r] + redsm[1][q * 4 + r] +
                        redsm[2][q * 4 + r] + redsm[3][q * 4 + r]);

    v4f o[2];
    #pragma unroll
    for (int ct = 0; ct < 2; ++ct)
        #pragma unroll
        for (int r = 0; r < 4; ++r) o[ct][r] = 0.f;

    for (int s = 0; s < 18; ++s) {
        int cm = s * 4 + q;
        v8s a = *(const v8s*)&P[l15 * 576 + ((cm ^ (l15 & 7)) << 3)];
        #pragma unroll
        for (int ct = 0; ct < 2; ++ct) {
            int c = (wave * 2 + ct) * 16 + l15;
            v8s b = *(const v8s*)(Vp + (size_t)c * 576 + s * 32 + q * 8);
            o[ct] = __builtin_amdgcn_mfma_f32_16x16x32_bf16(a, b, o[ct], 0, 0, 0);
        }
    }

    #pragma unroll
    for (int ct = 0; ct < 2; ++ct) {
        int c = (wave * 2 + ct) * 16 + l15;
        size_t base = ((size_t)p * 128 + c) * 576 + n0 + q * 4;
        if (MODE == 0) {
            float al = alpha[0];
            #pragma unroll
            for (int r = 0; r < 4; ++r)
                Of[base + r] = al * o[ct][r] * inv[r] + addsrc[base + r];
        } else {
            #pragma unroll
            for (int r = 0; r < 4; ++r)
                Oh[base + r] = f2bf(o[ct][r] * inv[r]);
        }
    }
}

// ------------------------------------- window sums for analytic gate-conv mean
__global__ __launch_bounds__(64) void wsum_kernel(
    const unsigned short* __restrict__ mji, float* __restrict__ wsum)
{
    int pair = blockIdx.x, ci = blockIdx.y, lane = threadIdx.x;
    const unsigned short* p = mji + ((size_t)pair * C_ + ci) * N_;
    float T=0, R0=0, R23=0, Cl=0, Cr=0, c00=0, c0w=0, ch0=0, chw=0;
    for (int i = lane; i < N_; i += 64) {
        float v = bf2f(p[i]);
        int r = i / 24, cc = i % 24;
        T += v;
        if (r == 0)  R0  += v;
        if (r == 23) R23 += v;
        if (cc == 0)  Cl += v;
        if (cc == 23) Cr += v;
        if (i == 0)   c00 = v;
        if (i == 23)  c0w = v;
        if (i == 552) ch0 = v;
        if (i == 575) chw = v;
    }
    #pragma unroll
    for (int off = 32; off > 0; off >>= 1) {
        T  += __shfl_xor(T, off);  R0 += __shfl_xor(R0, off);  R23 += __shfl_xor(R23, off);
        Cl += __shfl_xor(Cl, off); Cr += __shfl_xor(Cr, off);
        c00 += __shfl_xor(c00, off); c0w += __shfl_xor(c0w, off);
        ch0 += __shfl_xor(ch0, off); chw += __shfl_xor(chw, off);
    }
    if (lane == 0) {
        float rowsub[3] = {R23, 0.f, R0};
        float colsub[3] = {Cr,  0.f, Cl};
        float corner[9] = {chw, 0.f, ch0,  0.f, 0.f, 0.f,  c0w, 0.f, c00};
        float* o = wsum + ((size_t)pair * C_ + ci) * 9;
        #pragma unroll
        for (int ky = 0; ky < 3; ++ky)
            #pragma unroll
            for (int kx = 0; kx < 3; ++kx)
                o[ky * 3 + kx] = T - rowsub[ky] - colsub[kx] + corner[ky * 3 + kx];
    }
}

__global__ __launch_bounds__(128) void g_kernel(
    const float* __restrict__ wsum, const float* __restrict__ Wg,
    const float* __restrict__ Wgb, float* __restrict__ g)
{
    __shared__ float sw[C_ * 9];
    int pair = blockIdx.x; int co = threadIdx.x;
    for (int i = co; i < C_ * 9; i += 128) sw[i] = wsum[(size_t)pair * C_ * 9 + i];
    __syncthreads();
    const float* w = Wg + (size_t)co * C_ * 9;
    float acc = 0.f;
    for (int i = 0; i < C_ * 9; ++i) acc += w[i] * sw[i];
    float m = acc * (1.f / 576.f) + Wgb[co];
    g[pair * C_ + co] = 1.f / (1.f + __expf(-m));
}

__global__ void msg_kernel(
    const float* __restrict__ eii, const unsigned short* __restrict__ mji,
    const float* __restrict__ g, const float* __restrict__ bn_gamma,
    const float* __restrict__ bn_beta, const float* __restrict__ intra_w,
    const float* __restrict__ inter_w, float* __restrict__ msg)
{
    int e = blockIdx.x * blockDim.x + threadIdx.x;
    if (e >= SB * C_ * N_) return;
    int n = e % N_;
    int c = (e / N_) % C_;
    int img = e / (N_ * C_);
    int s = img >> 1, b = img & 1;
    float scale = bn_gamma[c] * rsqrtf(1.f + 1e-5f);
    float acc = 0.f;
    #pragma unroll
    for (int jj = 0; jj < 4; ++jj) {
        int pidx = (s * 4 + jj) * 2 + b;
        acc += g[pidx * C_ + c] * bf2f(mji[((size_t)pidx * C_ + c) * N_ + n]);
    }
    float inter = scale * acc + 4.f * bn_beta[c];
    msg[e] = intra_w[0] * eii[e] + inter_w[0] * inter;
}

// update: z from 4 zr partial planes, hhat from 4 h partial planes
__global__ void update_kernel(const float* __restrict__ zrp, const float* __restrict__ zrb,
                              const float* __restrict__ hhp, const float* __restrict__ ghb,
                              const float* __restrict__ h, float* __restrict__ out)
{
    const size_t ZP = (size_t)SB * C2 * N_;
    const size_t HP = (size_t)SB * C_ * N_;
    int e = blockIdx.x * blockDim.x + threadIdx.x;
    if (e >= SB * C_ * N_) return;
    int n = e % N_;
    int c = (e / N_) % C_;
    int img = e / (N_ * C_);
    size_t zi = ((size_t)img * C2 + c) * N_ + n;
    float za = zrb[c];
    #pragma unroll
    for (int k = 0; k < 4; ++k) za += zrp[k * ZP + zi];
    float z = 1.f / (1.f + __expf(-za));
    size_t hi = ((size_t)img * C_ + c) * N_ + n;
    float ha = ghb[c];
    #pragma unroll
    for (int k = 0; k < 4; ++k) ha += hhp[k * HP + hi];
    float hh = tanhf(ha);
    out[e] = (2.f - z) * h[e] + z * hh;
}

// ------------------------------------------------------------------- launcher
extern "C" void kernel_launch(void* const* d_in, const int* in_sizes, int n_in,
                              void* d_out, int out_size, void* d_ws, size_t ws_size,
                              hipStream_t stream)
{
    const float* x      = (const float*)d_in[0];
    const float* Wf_w   = (const float*)d_in[1];
    const float* Wf_b   = (const float*)d_in[2];
    const float* Wh_w   = (const float*)d_in[3];
    const float* Wh_b   = (const float*)d_in[4];
    const float* Wl_w   = (const float*)d_in[5];
    const float* Wl_b   = (const float*)d_in[6];
    const float* alpha  = (const float*)d_in[7];
    const float* Wc     = (const float*)d_in[8];
    const float* Wg_w   = (const float*)d_in[9];
    const float* Wg_b   = (const float*)d_in[10];
    const float* bng    = (const float*)d_in[11];
    const float* bnb    = (const float*)d_in[12];
    const float* zr_w   = (const float*)d_in[13];
    const float* zr_b   = (const float*)d_in[14];
    const float* gh_w   = (const float*)d_in[15];
    const float* gh_b   = (const float*)d_in[16];
    const float* intraw = (const float*)d_in[17];
    const float* interw = (const float*)d_in[18];
    float* outp = (float*)d_out;

    float* f = (float*)d_ws;
    const size_t SZ = (size_t)SB * C_ * N_;
    float* hbuf  = f; f += SZ;
    float* eii   = f; f += SZ;                       // msg written in-place
    float* zrp   = f; f += 4 * (size_t)SB * C2 * N_; // 4 partial planes (zr)
    float* hhp   = f; f += 4 * SZ;                   // 4 partial planes (h)
    float* wsumb = f; f += (size_t)NPAIR * C_ * 9;
    float* gbuf  = f; f += (size_t)NPAIR * C_;
    float* po3   = zrp;                              // alias: dead before zr conv writes
    unsigned short* us = (unsigned short*)f;
    unsigned short* mji16  = us; us += (size_t)NPAIR * C_ * N_;
    unsigned short* hT16   = us; us += SZ;
    unsigned short* hc16   = us; us += SZ;           // also reused as rhbT16
    unsigned short* msgT16 = us; us += SZ;
    unsigned short* ftT    = us; us += SZ;           // also reused as ytT
    unsigned short* htT    = us; us += SZ;
    unsigned short* lt16   = us; us += SZ;
    unsigned short* Wp3    = us; us += (size_t)384 * 1152;
    unsigned short* Wpzr   = us; us += (size_t)256 * 6400;
    unsigned short* Wph    = us; us += (size_t)128 * 6400;
    unsigned short* Wcb    = us; us += (size_t)128 * 128;

    unsigned short* ytT    = ftT;
    unsigned short* rhbT16 = hc16;

    const int NELEM = SB * C_ * N_;
    dim3 eb((NELEM + 255) / 256);

    packA3_kernel<<<(384 * 1152 + 255) / 256, 256, 0, stream>>>(Wf_w, Wh_w, Wl_w, Wp3);
    packA5_kernel<<<(256 * 6400 + 255) / 256, 256, 0, stream>>>(zr_w, Wpzr, 256);
    packA5_kernel<<<(128 * 6400 + 255) / 256, 256, 0, stream>>>(gh_w, Wph, 128);
    packWc_kernel<<<64, 256, 0, stream>>>(Wc, Wcb);

    const float* hcur = x;
    for (int it = 0; it < 3; ++it) {
        float* hout = (it == 2) ? outp : hbuf;
        float* msg = eii;

        tc_kernel<<<dim3(9, SB), 256, 0, stream>>>(hcur, nullptr, nullptr, hT16, hc16);
        conv_mfma<3, 1, 128><<<dim3(12, 3, SB), 256, 0, stream>>>(
            hT16, hT16, Wp3, 384, po3);
        combine3_kernel<<<dim3(9, SB), 256, 0, stream>>>(po3, Wf_b, Wh_b, Wl_b, ftT, htT, lt16);
        attn_mfma<0><<<dim3(36, SB), 256, 0, stream>>>(ftT, htT, lt16, eii, nullptr, hcur, alpha);
        yt_mfma<<<dim3(36, SB), 256, 0, stream>>>(hT16, Wcb, ytT);
        attn_mfma<1><<<dim3(36, NPAIR), 256, 0, stream>>>(hT16, ytT, hc16, nullptr, mji16, nullptr, nullptr);
        wsum_kernel<<<dim3(NPAIR, C_), 64, 0, stream>>>(mji16, wsumb);
        g_kernel<<<NPAIR, 128, 0, stream>>>(wsumb, Wg_w, Wg_b, gbuf);
        msg_kernel<<<eb, 256, 0, stream>>>(eii, mji16, gbuf, bng, bnb, intraw, interw, msg);
        tc_kernel<<<dim3(9, SB), 256, 0, stream>>>(msg, nullptr, nullptr, msgT16, nullptr);
        conv_mfma<5, 2, 256><<<dim3(16, 3, SB), 256, 0, stream>>>(
            msgT16, hT16, Wpzr, 256, zrp);
        tc_kernel<<<dim3(9, SB), 256, 0, stream>>>(hcur, zrp, zr_b, rhbT16, nullptr);
        conv_mfma<5, 2, 256><<<dim3(8, 3, SB), 256, 0, stream>>>(
            msgT16, rhbT16, Wph, 128, hhp);
        update_kernel<<<eb, 256, 0, stream>>>(zrp, zr_b, hhp, gh_b, hcur, hout);
        hcur = hout;
    }
}

// Round 10
// 665.074 us; speedup vs baseline: 1.8545x; 1.2878x over previous
//
#include <hip/hip_runtime.h>
#include <math.h>

#define S_  5
#define B_  2
#define C_  128
#define N_  576
#define SB  10
#define NPAIR 40
#define C2  256

typedef short v8s __attribute__((ext_vector_type(8)));
typedef float v4f __attribute__((ext_vector_type(4)));

#define GLOBAL_AS __attribute__((address_space(1)))
#define LDS_AS    __attribute__((address_space(3)))

__device__ __forceinline__ unsigned short f2bf(float f) {
    union { float f; unsigned u; } v; v.f = f;
    unsigned r = (v.u + 0x7FFF + ((v.u >> 16) & 1)) >> 16;
    return (unsigned short)r;
}
__device__ __forceinline__ float bf2f(unsigned short h) {
    union { unsigned u; float f; } v; v.u = ((unsigned)h) << 16;
    return v.f;
}

// ------------------------------------------------------------------ weight packs
// Fragment-major A layout: [cgb][kk(SPLITK)][ch(2)][g(KD)][tap_l(KD)][c(4)][l15(16)][quad(4)][j(8)]
__global__ void packA5_kernel(const float* __restrict__ w, unsigned short* __restrict__ Apk, int M)
{
    int idx = blockIdx.x * 256 + threadIdx.x;
    if (idx >= M * 6400) return;
    int r = idx;
    int j = r & 7;      r >>= 3;
    int quad = r & 3;   r >>= 2;
    int l15 = r & 15;   r >>= 4;
    int c = r & 3;      r >>= 2;
    int tap_l = r % 5;  r /= 5;
    int g = r % 5;      r /= 5;
    int ch = r & 1;     r >>= 1;
    int kk = r & 3;     r >>= 2;
    int cgb = r;
    int co = cgb * 64 + c * 16 + l15;
    int ci = kk * 64 + ch * 32 + quad * 8 + j;
    int tap = g * 5 + tap_l;
    Apk[idx] = f2bf(w[((size_t)co * 256 + ci) * 25 + tap]);
}
__global__ void packA3_kernel(const float* __restrict__ wf, const float* __restrict__ wh,
                              const float* __restrict__ wl, unsigned short* __restrict__ Apk)
{
    int idx = blockIdx.x * 256 + threadIdx.x;
    if (idx >= 384 * 1152) return;
    int r = idx;
    int j = r & 7;      r >>= 3;
    int quad = r & 3;   r >>= 2;
    int l15 = r & 15;   r >>= 4;
    int c = r & 3;      r >>= 2;
    int tap_l = r % 3;  r /= 3;
    int g = r % 3;      r /= 3;
    int ch = r & 1;     r >>= 1;
    int kk = r & 1;     r >>= 1;
    int cgb = r;
    int co = cgb * 64 + c * 16 + l15;
    const float* w = (co < 128) ? wf : (co < 256) ? wh : wl;
    int cl = co & 127;
    int ci = kk * 64 + ch * 32 + quad * 8 + j;
    int tap = g * 3 + tap_l;
    Apk[idx] = f2bf(w[((size_t)cl * 128 + ci) * 9 + tap]);
}
__global__ void packWc_kernel(const float* __restrict__ w, unsigned short* __restrict__ o)
{
    int idx = blockIdx.x * 256 + threadIdx.x;
    if (idx < 128 * 128) o[idx] = f2bf(w[idx]);
}

// ---------------------------------------------- transpose-cast: [c][px] f32 -> [px][c] bf16
// zrp != null: multiply by r = sigmoid(sum_{k<4} zrp[k][128+c] + zrb[128+c])
// vfd != null: also emit V-fragment-packed bf16 (for inter-attn PV)
__global__ __launch_bounds__(256) void tc_kernel(
    const float* __restrict__ src, const float* __restrict__ zrp,
    const float* __restrict__ zrb,
    unsigned short* __restrict__ dst, unsigned short* __restrict__ vfd)
{
    const size_t PLANE = (size_t)SB * C2 * N_;
    __shared__ float tile[128][65];
    int img = blockIdx.y, px0 = blockIdx.x * 64, t = threadIdx.x;
    #pragma unroll
    for (int i = 0; i < 32; ++i) {
        int e = i * 256 + t; int ci = e >> 6; int px = e & 63;
        float v = src[((size_t)img * 128 + ci) * 576 + px0 + px];
        if (zrp) {
            size_t zi = ((size_t)img * C2 + 128 + ci) * 576 + px0 + px;
            float a = zrb[128 + ci];
            #pragma unroll
            for (int k = 0; k < 4; ++k) a += zrp[k * PLANE + zi];
            v *= 1.f / (1.f + __expf(-a));
        }
        tile[ci][px] = v;
        if (vfd) {
            int m = px0 + px;
            int ctile = ci >> 4, l15v = ci & 15;
            int sIdx = m >> 5, quadv = (m >> 3) & 3, j = m & 7;
            vfd[(((size_t)img * 8 + ctile) * 18 + sIdx) * 512 + (quadv * 16 + l15v) * 8 + j] = f2bf(v);
        }
    }
    __syncthreads();
    #pragma unroll
    for (int i = 0; i < 32; ++i) {
        int e = i * 256 + t; int px = e >> 7; int ci = e & 127;
        dst[((size_t)img * 576 + px0 + px) * 128 + ci] = f2bf(tile[ci][px]);
    }
}

// ------------------------------------------------------ MFMA implicit-GEMM conv v6
template<int KD, int R, int CINT>
__global__ __launch_bounds__(256, 1) void conv_mfma(
    const unsigned short* __restrict__ srcA, const unsigned short* __restrict__ srcB,
    const unsigned short* __restrict__ Apk, int COUT, float* __restrict__ po)
{
    constexpr int SPLITK = CINT / 64;
    constexpr int NCH    = 2;
    constexpr int NSUB   = NCH * KD;
    constexpr int WR     = 8 + 2 * R;
    constexpr int WC     = 24 + 2 * R;
    constexpr int NPOS   = WR * WC;
    constexpr int NSLOTB = NPOS * 4;
    constexpr int RB     = (NSLOTB + 255) / 256;
    constexpr int AUNITS = KD * 4 * 64;
    constexpr int AR     = AUNITS / 256;
    __shared__ __align__(16) unsigned short Ab[2][AUNITS * 8];
    __shared__ __align__(16) unsigned short Bb[NPOS * 32];

    int f   = blockIdx.x;
    int kk  = f % SPLITK;
    int cgb = f / SPLITK;
    int pxb = blockIdx.y;
    int img = blockIdx.z;
    int t = threadIdx.x;
    int wave = t >> 6, lane = t & 63;
    int quad = lane >> 4, l15 = lane & 15;
    int r0 = pxb * 8;

    const int cibase = kk * 64;
    const unsigned short* src = (cibase >= 128) ? srcB : srcA;
    const int cioff0 = cibase & 127;
    const unsigned short* srcI = src + (size_t)img * 576 * 128;

    int posBase[3], pxs[3];
    #pragma unroll
    for (int s = 0; s < 3; ++s) {
        int px = pxb * 192 + wave * 48 + s * 16 + l15;
        pxs[s] = px;
        int pr = px / 24, pc = px % 24;
        posBase[s] = (pr - r0 + R) * WC + pc + R;
    }

    int goffB[RB]; bool gokB[RB];
    #pragma unroll
    for (int rr = 0; rr < RB; ++rr) {
        int idx = rr * 256 + wave * 64 + lane;
        int pos = idx >> 2, slotq = idx & 3;
        int gr = slotq ^ ((pos >> 1) & 3);
        int wr = pos / WC, wc = pos % WC;
        int grow = r0 - R + wr, gcol = wc - R;
        gokB[rr] = (idx < NSLOTB) && grow >= 0 && grow < 24 && gcol >= 0 && gcol < 24;
        goffB[rr] = (grow * 24 + gcol) * 128 + gr * 8;
    }

    auto stageB = [&](int ch) {
        const unsigned short* sp = srcI + cioff0 + ch * 32;
        #pragma unroll
        for (int rr = 0; rr < RB; ++rr) {
            if (gokB[rr]) {
                __builtin_amdgcn_global_load_lds(
                    (const GLOBAL_AS void*)(sp + goffB[rr]),
                    (LDS_AS void*)((char*)&Bb[0] + (size_t)(rr * 256 + wave * 64) * 16),
                    16, 0, 0);
            }
        }
    };
    auto stageA = [&](int sub, int buf) {
        const unsigned short* sp = Apk + ((size_t)((cgb * SPLITK + kk) * NSUB + sub)) * (AUNITS * 8);
        #pragma unroll
        for (int r = 0; r < AR; ++r) {
            int u0 = r * 256 + wave * 64;
            __builtin_amdgcn_global_load_lds(
                (const GLOBAL_AS void*)(sp + (size_t)(u0 + lane) * 8),
                (LDS_AS void*)((char*)&Ab[buf][0] + (size_t)u0 * 16),
                16, 0, 0);
        }
    };

    v4f acc[4][3];
    #pragma unroll
    for (int c = 0; c < 4; ++c)
        #pragma unroll
        for (int s = 0; s < 3; ++s)
            #pragma unroll
            for (int r = 0; r < 4; ++r) acc[c][s][r] = 0.f;

    {
        v8s zv;
        #pragma unroll
        for (int j = 0; j < 8; ++j) zv[j] = 0;
        for (int i = t; i < NPOS * 4; i += 256) ((v8s*)Bb)[i] = zv;
    }
    __syncthreads();
    stageB(0);
    stageA(0, 0);
    __syncthreads();

    int sub = 0;
    #pragma unroll 1
    for (int ch = 0; ch < NCH; ++ch) {
        #pragma unroll 1
        for (int g = 0; g < KD; ++g) {
            if (sub + 1 < NSUB) stageA(sub + 1, (sub + 1) & 1);
            const unsigned short* Ap = &Ab[sub & 1][0];
            #pragma unroll
            for (int tl = 0; tl < KD; ++tl) {
                int doff = (g - R) * WC + (tl - R);
                v8s a[4];
                #pragma unroll
                for (int c = 0; c < 4; ++c)
                    a[c] = *(const v8s*)&Ap[((tl * 4 + c) * 64 + l15 * 4 + quad) * 8];
                v8s b[3];
                #pragma unroll
                for (int s = 0; s < 3; ++s) {
                    int pos = posBase[s] + doff;
                    b[s] = *(const v8s*)&Bb[pos * 32 + ((quad ^ ((pos >> 1) & 3)) << 3)];
                }
                #pragma unroll
                for (int c = 0; c < 4; ++c)
                    #pragma unroll
                    for (int s = 0; s < 3; ++s)
                        acc[c][s] = __builtin_amdgcn_mfma_f32_16x16x32_bf16(a[c], b[s], acc[c][s], 0, 0, 0);
            }
            __syncthreads();
            ++sub;
        }
        if (ch + 1 < NCH) { stageB(ch + 1); __syncthreads(); }
    }

    float* out = po + (size_t)kk * ((size_t)SB * COUT * 576)
               + ((size_t)img * COUT + cgb * 64) * 576;
    #pragma unroll
    for (int c = 0; c < 4; ++c)
        #pragma unroll
        for (int s = 0; s < 3; ++s)
            #pragma unroll
            for (int r = 0; r < 4; ++r) {
                int col = c * 16 + quad * 4 + r;
                out[(size_t)col * 576 + pxs[s]] = acc[c][s][r];
            }
}

// ------------- combine conv3 partials -> ftT (Q) / KFa (K-packed) / VFa (V-packed)
__global__ __launch_bounds__(256) void combine3_kernel(
    const float* __restrict__ po3, const float* __restrict__ bf_,
    const float* __restrict__ bh_, const float* __restrict__ bl_,
    unsigned short* __restrict__ ftT, unsigned short* __restrict__ KFa,
    unsigned short* __restrict__ VFa)
{
    const size_t P3 = (size_t)SB * 384 * N_;
    __shared__ float tile[128][65];
    int img = blockIdx.y, px0 = blockIdx.x * 64, t = threadIdx.x;

    // ft -> Q layout [px][128]
    #pragma unroll
    for (int i = 0; i < 32; ++i) {
        int e = i * 256 + t; int cl = e >> 6; int pxl = e & 63;
        size_t idx = ((size_t)img * 384 + cl) * N_ + px0 + pxl;
        tile[cl][pxl] = po3[idx] + po3[P3 + idx] + bf_[cl];
    }
    __syncthreads();
    #pragma unroll
    for (int i = 0; i < 32; ++i) {
        int e = i * 256 + t; int pxl = e >> 7; int cl = e & 127;
        ftT[((size_t)img * N_ + px0 + pxl) * 128 + cl] = f2bf(tile[cl][pxl]);
    }
    __syncthreads();
    // ht -> K fragment pack
    #pragma unroll
    for (int i = 0; i < 32; ++i) {
        int e = i * 256 + t; int cl = e >> 6; int pxl = e & 63;
        size_t idx = ((size_t)img * 384 + 128 + cl) * N_ + px0 + pxl;
        tile[cl][pxl] = po3[idx] + po3[P3 + idx] + bh_[cl];
    }
    __syncthreads();
    #pragma unroll
    for (int i = 0; i < 32; ++i) {
        int e = i * 256 + t; int pxl = e >> 7; int cl = e & 127;
        int m = px0 + pxl;
        int mt = m >> 4, l15m = m & 15;
        int kk = cl >> 5, quadk = (cl >> 3) & 3, j = cl & 7;
        KFa[(((size_t)img * 36 + mt) * 4 + kk) * 512 + (quadk * 16 + l15m) * 8 + j]
            = f2bf(tile[cl][pxl]);
    }
    // lt -> V fragment pack (j = m&7 contiguous in this loop order)
    #pragma unroll
    for (int i = 0; i < 32; ++i) {
        int e = i * 256 + t; int cl = e >> 6; int pxl = e & 63;
        size_t idx = ((size_t)img * 384 + 256 + cl) * N_ + px0 + pxl;
        float v = po3[idx] + po3[P3 + idx] + bl_[cl];
        int m = px0 + pxl;
        int ctile = cl >> 4, l15v = cl & 15;
        int sIdx = m >> 5, quadv = (m >> 3) & 3, j = m & 7;
        VFa[(((size_t)img * 8 + ctile) * 18 + sIdx) * 512 + (quadv * 16 + l15v) * 8 + j] = f2bf(v);
    }
}

// ---------------------------------------------------------------- yt (MFMA) -> K-packed
__global__ __launch_bounds__(256) void yt_mfma(
    const unsigned short* __restrict__ hT, const unsigned short* __restrict__ Wcb,
    unsigned short* __restrict__ KFi)
{
    int t = threadIdx.x, wave = t >> 6, lane = t & 63;
    int q = lane >> 4, l15 = lane & 15;
    int n0 = blockIdx.x * 16, img = blockIdx.y;
    v4f acc[2];
    #pragma unroll
    for (int ct = 0; ct < 2; ++ct)
        #pragma unroll
        for (int r = 0; r < 4; ++r) acc[ct][r] = 0.f;
    #pragma unroll
    for (int kk = 0; kk < 4; ++kk) {
        v8s b = *(const v8s*)(hT + ((size_t)img * 576 + n0 + l15) * 128 + kk * 32 + q * 8);
        #pragma unroll
        for (int ct = 0; ct < 2; ++ct) {
            v8s a = *(const v8s*)(Wcb + (size_t)((wave * 2 + ct) * 16 + l15) * 128 + kk * 32 + q * 8);
            acc[ct] = __builtin_amdgcn_mfma_f32_16x16x32_bf16(a, b, acc[ct], 0, 0, 0);
        }
    }
    int mt = blockIdx.x;
    #pragma unroll
    for (int ct = 0; ct < 2; ++ct) {
        #pragma unroll
        for (int r = 0; r < 4; ++r) {
            int co = (wave * 2 + ct) * 16 + q * 4 + r;
            int kk = co >> 5, quadk = (co >> 3) & 3, j = co & 7;
            KFi[(((size_t)img * 36 + mt) * 4 + kk) * 512 + (quadk * 16 + l15) * 8 + j]
                = f2bf(acc[ct][r]);
        }
    }
}

// ---------------------------------------------------- MFMA flash attention
// K and V consumed from fragment-packed layouts (coalesced lane*16B loads)
template<int MODE>
__global__ __launch_bounds__(256) void attn_mfma(
    const unsigned short* __restrict__ QT, const unsigned short* __restrict__ KF,
    const unsigned short* __restrict__ VF, float* __restrict__ Of,
    unsigned short* __restrict__ Oh, const float* __restrict__ addsrc,
    const float* __restrict__ alpha)
{
    __shared__ __align__(16) unsigned short P[16 * 576];
    __shared__ float redmx[4][16];
    __shared__ float redsm[4][16];
    int t = threadIdx.x;
    int wave = t >> 6, lane = t & 63;
    int q = lane >> 4, l15 = lane & 15;
    int n0 = blockIdx.x * 16;
    int p = blockIdx.y;
    int qimg, kimg;
    if (MODE == 0) { qimg = p; kimg = p; }
    else {
        int b = p & 1; int ij = p >> 1; int i = ij >> 2; int jj = ij & 3;
        int j = jj + (jj >= i ? 1 : 0);
        qimg = i * 2 + b; kimg = j * 2 + b;
    }
    const unsigned short* Qp = QT + ((size_t)qimg * 576 + n0) * 128;
    const unsigned short* Kp = KF + (size_t)kimg * 36 * 4 * 512;
    const unsigned short* Vp = VF + (size_t)kimg * 8 * 18 * 512;

    v8s aq[4];
    #pragma unroll
    for (int kk = 0; kk < 4; ++kk)
        aq[kk] = *(const v8s*)(Qp + (size_t)l15 * 128 + kk * 32 + q * 8);

    v4f S[9];
    #pragma unroll
    for (int i = 0; i < 9; ++i)
        #pragma unroll
        for (int r = 0; r < 4; ++r) S[i][r] = 0.f;

    #pragma unroll
    for (int i = 0; i < 9; ++i) {
        int mt = wave * 9 + i;
        #pragma unroll
        for (int kk = 0; kk < 4; ++kk) {
            v8s b = *(const v8s*)(Kp + ((size_t)(mt * 4 + kk)) * 512 + lane * 8);
            S[i] = __builtin_amdgcn_mfma_f32_16x16x32_bf16(aq[kk], b, S[i], 0, 0, 0);
        }
    }

    float mx[4];
    #pragma unroll
    for (int r = 0; r < 4; ++r) {
        float m = S[0][r];
        #pragma unroll
        for (int i = 1; i < 9; ++i) m = fmaxf(m, S[i][r]);
        #pragma unroll
        for (int off = 1; off < 16; off <<= 1) m = fmaxf(m, __shfl_xor(m, off));
        mx[r] = m;
    }
    if (l15 == 0) {
        #pragma unroll
        for (int r = 0; r < 4; ++r) redmx[wave][q * 4 + r] = mx[r];
    }
    __syncthreads();
    float sum[4];
    #pragma unroll
    for (int r = 0; r < 4; ++r) {
        float g = fmaxf(fmaxf(redmx[0][q * 4 + r], redmx[1][q * 4 + r]),
                        fmaxf(redmx[2][q * 4 + r], redmx[3][q * 4 + r]));
        float s = 0.f;
        #pragma unroll
        for (int i = 0; i < 9; ++i) { float e = __expf(S[i][r] - g); S[i][r] = e; s += e; }
        #pragma unroll
        for (int off = 1; off < 16; off <<= 1) s += __shfl_xor(s, off);
        sum[r] = s;
    }
    if (l15 == 0) {
        #pragma unroll
        for (int r = 0; r < 4; ++r) redsm[wave][q * 4 + r] = sum[r];
    }
    #pragma unroll
    for (int i = 0; i < 9; ++i) {
        int m = (wave * 9 + i) * 16 + l15;
        int cm = m >> 3, mo = m & 7;
        #pragma unroll
        for (int r = 0; r < 4; ++r) {
            int n = q * 4 + r;
            P[n * 576 + ((cm ^ (n & 7)) << 3) + mo] = f2bf(S[i][r]);
        }
    }
    __syncthreads();
    float inv[4];
    #pragma unroll
    for (int r = 0; r < 4; ++r)
        inv[r] = 1.f / (redsm[0][q * 4 + r] + redsm[1][q * 4 + r] +
                        redsm[2][q * 4 + r] + redsm[3][q * 4 + r]);

    v4f o[2];
    #pragma unroll
    for (int ct = 0; ct < 2; ++ct)
        #pragma unroll
        for (int r = 0; r < 4; ++r) o[ct][r] = 0.f;

    for (int s = 0; s < 18; ++s) {
        int cm = s * 4 + q;
        v8s a = *(const v8s*)&P[l15 * 576 + ((cm ^ (l15 & 7)) << 3)];
        #pragma unroll
        for (int ct = 0; ct < 2; ++ct) {
            int ctile = wave * 2 + ct;
            v8s b = *(const v8s*)(Vp + ((size_t)(ctile * 18 + s)) * 512 + lane * 8);
            o[ct] = __builtin_amdgcn_mfma_f32_16x16x32_bf16(a, b, o[ct], 0, 0, 0);
        }
    }

    #pragma unroll
    for (int ct = 0; ct < 2; ++ct) {
        int c = (wave * 2 + ct) * 16 + l15;
        size_t base = ((size_t)p * 128 + c) * 576 + n0 + q * 4;
        if (MODE == 0) {
            float al = alpha[0];
            #pragma unroll
            for (int r = 0; r < 4; ++r)
                Of[base + r] = al * o[ct][r] * inv[r] + addsrc[base + r];
        } else {
            #pragma unroll
            for (int r = 0; r < 4; ++r)
                Oh[base + r] = f2bf(o[ct][r] * inv[r]);
        }
    }
}

// ------------------------------------- window sums for analytic gate-conv mean
__global__ __launch_bounds__(64) void wsum_kernel(
    const unsigned short* __restrict__ mji, float* __restrict__ wsum)
{
    int pair = blockIdx.x, ci = blockIdx.y, lane = threadIdx.x;
    const unsigned short* p = mji + ((size_t)pair * C_ + ci) * N_;
    float T=0, R0=0, R23=0, Cl=0, Cr=0, c00=0, c0w=0, ch0=0, chw=0;
    for (int i = lane; i < N_; i += 64) {
        float v = bf2f(p[i]);
        int r = i / 24, cc = i % 24;
        T += v;
        if (r == 0)  R0  += v;
        if (r == 23) R23 += v;
        if (cc == 0)  Cl += v;
        if (cc == 23) Cr += v;
        if (i == 0)   c00 = v;
        if (i == 23)  c0w = v;
        if (i == 552) ch0 = v;
        if (i == 575) chw = v;
    }
    #pragma unroll
    for (int off = 32; off > 0; off >>= 1) {
        T  += __shfl_xor(T, off);  R0 += __shfl_xor(R0, off);  R23 += __shfl_xor(R23, off);
        Cl += __shfl_xor(Cl, off); Cr += __shfl_xor(Cr, off);
        c00 += __shfl_xor(c00, off); c0w += __shfl_xor(c0w, off);
        ch0 += __shfl_xor(ch0, off); chw += __shfl_xor(chw, off);
    }
    if (lane == 0) {
        float rowsub[3] = {R23, 0.f, R0};
        float colsub[3] = {Cr,  0.f, Cl};
        float corner[9] = {chw, 0.f, ch0,  0.f, 0.f, 0.f,  c0w, 0.f, c00};
        float* o = wsum + ((size_t)pair * C_ + ci) * 9;
        #pragma unroll
        for (int ky = 0; ky < 3; ++ky)
            #pragma unroll
            for (int kx = 0; kx < 3; ++kx)
                o[ky * 3 + kx] = T - rowsub[ky] - colsub[kx] + corner[ky * 3 + kx];
    }
}

__global__ __launch_bounds__(128) void g_kernel(
    const float* __restrict__ wsum, const float* __restrict__ Wg,
    const float* __restrict__ Wgb, float* __restrict__ g)
{
    __shared__ float sw[C_ * 9];
    int pair = blockIdx.x; int co = threadIdx.x;
    for (int i = co; i < C_ * 9; i += 128) sw[i] = wsum[(size_t)pair * C_ * 9 + i];
    __syncthreads();
    const float* w = Wg + (size_t)co * C_ * 9;
    float acc = 0.f;
    for (int i = 0; i < C_ * 9; ++i) acc += w[i] * sw[i];
    float m = acc * (1.f / 576.f) + Wgb[co];
    g[pair * C_ + co] = 1.f / (1.f + __expf(-m));
}

__global__ void msg_kernel(
    const float* __restrict__ eii, const unsigned short* __restrict__ mji,
    const float* __restrict__ g, const float* __restrict__ bn_gamma,
    const float* __restrict__ bn_beta, const float* __restrict__ intra_w,
    const float* __restrict__ inter_w, float* __restrict__ msg)
{
    int e = blockIdx.x * blockDim.x + threadIdx.x;
    if (e >= SB * C_ * N_) return;
    int n = e % N_;
    int c = (e / N_) % C_;
    int img = e / (N_ * C_);
    int s = img >> 1, b = img & 1;
    float scale = bn_gamma[c] * rsqrtf(1.f + 1e-5f);
    float acc = 0.f;
    #pragma unroll
    for (int jj = 0; jj < 4; ++jj) {
        int pidx = (s * 4 + jj) * 2 + b;
        acc += g[pidx * C_ + c] * bf2f(mji[((size_t)pidx * C_ + c) * N_ + n]);
    }
    float inter = scale * acc + 4.f * bn_beta[c];
    msg[e] = intra_w[0] * eii[e] + inter_w[0] * inter;
}

// update: z from 4 zr partial planes, hhat from 4 h partial planes
__global__ void update_kernel(const float* __restrict__ zrp, const float* __restrict__ zrb,
                              const float* __restrict__ hhp, const float* __restrict__ ghb,
                              const float* __restrict__ h, float* __restrict__ out)
{
    const size_t ZP = (size_t)SB * C2 * N_;
    const size_t HP = (size_t)SB * C_ * N_;
    int e = blockIdx.x * blockDim.x + threadIdx.x;
    if (e >= SB * C_ * N_) return;
    int n = e % N_;
    int c = (e / N_) % C_;
    int img = e / (N_ * C_);
    size_t zi = ((size_t)img * C2 + c) * N_ + n;
    float za = zrb[c];
    #pragma unroll
    for (int k = 0; k < 4; ++k) za += zrp[k * ZP + zi];
    float z = 1.f / (1.f + __expf(-za));
    size_t hi = ((size_t)img * C_ + c) * N_ + n;
    float ha = ghb[c];
    #pragma unroll
    for (int k = 0; k < 4; ++k) ha += hhp[k * HP + hi];
    float hh = tanhf(ha);
    out[e] = (2.f - z) * h[e] + z * hh;
}

// ------------------------------------------------------------------- launcher
extern "C" void kernel_launch(void* const* d_in, const int* in_sizes, int n_in,
                              void* d_out, int out_size, void* d_ws, size_t ws_size,
                              hipStream_t stream)
{
    const float* x      = (const float*)d_in[0];
    const float* Wf_w   = (const float*)d_in[1];
    const float* Wf_b   = (const float*)d_in[2];
    const float* Wh_w   = (const float*)d_in[3];
    const float* Wh_b   = (const float*)d_in[4];
    const float* Wl_w   = (const float*)d_in[5];
    const float* Wl_b   = (const float*)d_in[6];
    const float* alpha  = (const float*)d_in[7];
    const float* Wc     = (const float*)d_in[8];
    const float* Wg_w   = (const float*)d_in[9];
    const float* Wg_b   = (const float*)d_in[10];
    const float* bng    = (const float*)d_in[11];
    const float* bnb    = (const float*)d_in[12];
    const float* zr_w   = (const float*)d_in[13];
    const float* zr_b   = (const float*)d_in[14];
    const float* gh_w   = (const float*)d_in[15];
    const float* gh_b   = (const float*)d_in[16];
    const float* intraw = (const float*)d_in[17];
    const float* interw = (const float*)d_in[18];
    float* outp = (float*)d_out;

    float* f = (float*)d_ws;
    const size_t SZ = (size_t)SB * C_ * N_;
    float* hbuf  = f; f += SZ;
    float* eii   = f; f += SZ;                       // msg written in-place
    float* zrp   = f; f += 4 * (size_t)SB * C2 * N_; // 4 partial planes (zr)
    float* hhp   = f; f += 4 * SZ;                   // 4 partial planes (h)
    float* wsumb = f; f += (size_t)NPAIR * C_ * 9;
    float* gbuf  = f; f += (size_t)NPAIR * C_;
    float* po3   = zrp;                              // alias: dead before zr conv writes
    unsigned short* us = (unsigned short*)f;
    unsigned short* mji16  = us; us += (size_t)NPAIR * C_ * N_;
    unsigned short* hT16   = us; us += SZ;
    unsigned short* hc16   = us; us += SZ;           // VF inter; reused as rhbT16
    unsigned short* msgT16 = us; us += SZ;
    unsigned short* ftT    = us; us += SZ;           // Q intra; reused as KF inter
    unsigned short* KFa    = us; us += SZ;           // K intra (fragment-packed)
    unsigned short* VFa    = us; us += SZ;           // V intra (fragment-packed)
    unsigned short* Wp3    = us; us += (size_t)384 * 1152;
    unsigned short* Wpzr   = us; us += (size_t)256 * 6400;
    unsigned short* Wph    = us; us += (size_t)128 * 6400;
    unsigned short* Wcb    = us; us += (size_t)128 * 128;

    unsigned short* KFi    = ftT;
    unsigned short* VFi    = hc16;
    unsigned short* rhbT16 = hc16;

    const int NELEM = SB * C_ * N_;
    dim3 eb((NELEM + 255) / 256);

    packA3_kernel<<<(384 * 1152 + 255) / 256, 256, 0, stream>>>(Wf_w, Wh_w, Wl_w, Wp3);
    packA5_kernel<<<(256 * 6400 + 255) / 256, 256, 0, stream>>>(zr_w, Wpzr, 256);
    packA5_kernel<<<(128 * 6400 + 255) / 256, 256, 0, stream>>>(gh_w, Wph, 128);
    packWc_kernel<<<64, 256, 0, stream>>>(Wc, Wcb);

    const float* hcur = x;
    for (int it = 0; it < 3; ++it) {
        float* hout = (it == 2) ? outp : hbuf;
        float* msg = eii;

        tc_kernel<<<dim3(9, SB), 256, 0, stream>>>(hcur, nullptr, nullptr, hT16, VFi);
        conv_mfma<3, 1, 128><<<dim3(12, 3, SB), 256, 0, stream>>>(
            hT16, hT16, Wp3, 384, po3);
        combine3_kernel<<<dim3(9, SB), 256, 0, stream>>>(po3, Wf_b, Wh_b, Wl_b, ftT, KFa, VFa);
        attn_mfma<0><<<dim3(36, SB), 256, 0, stream>>>(ftT, KFa, VFa, eii, nullptr, hcur, alpha);
        yt_mfma<<<dim3(36, SB), 256, 0, stream>>>(hT16, Wcb, KFi);
        attn_mfma<1><<<dim3(36, NPAIR), 256, 0, stream>>>(hT16, KFi, VFi, nullptr, mji16, nullptr, nullptr);
        wsum_kernel<<<dim3(NPAIR, C_), 64, 0, stream>>>(mji16, wsumb);
        g_kernel<<<NPAIR, 128, 0, stream>>>(wsumb, Wg_w, Wg_b, gbuf);
        msg_kernel<<<eb, 256, 0, stream>>>(eii, mji16, gbuf, bng, bnb, intraw, interw, msg);
        tc_kernel<<<dim3(9, SB), 256, 0, stream>>>(msg, nullptr, nullptr, msgT16, nullptr);
        conv_mfma<5, 2, 256><<<dim3(16, 3, SB), 256, 0, stream>>>(
            msgT16, hT16, Wpzr, 256, zrp);
        tc_kernel<<<dim3(9, SB), 256, 0, stream>>>(hcur, zrp, zr_b, rhbT16, nullptr);
        conv_mfma<5, 2, 256><<<dim3(8, 3, SB), 256, 0, stream>>>(
            msgT16, rhbT16, Wph, 128, hhp);
        update_kernel<<<eb, 256, 0, stream>>>(zrp, zr_b, hhp, gh_b, hcur, hout);
        hcur = hout;
    }
}